// Round 7
// baseline (1003.195 us; speedup 1.0000x reference)
//
#include <hip/hip_runtime.h>

#define NEG_SLOPE 0.2f

typedef __attribute__((ext_vector_type(8))) short short8;
typedef __attribute__((ext_vector_type(8))) unsigned short ushort8;
typedef __attribute__((ext_vector_type(4))) float f32x4;

__device__ __forceinline__ unsigned short f2bf(float f) {
    unsigned int u = __float_as_uint(f);
    u += 0x7fff + ((u >> 16) & 1);     // round-to-nearest-even
    return (unsigned short)(u >> 16);
}
__device__ __forceinline__ float bf2f(unsigned short s) {
    return __uint_as_float(((unsigned int)s) << 16);
}

// async global->LDS, 16B per lane; lds base must be wave-uniform
__device__ __forceinline__ void gll16(const void* g, void* l) {
    __builtin_amdgcn_global_load_lds(
        (const __attribute__((address_space(1))) void*)g,
        (__attribute__((address_space(3))) void*)l, 16, 0, 0);
}

// ---------------- converters ----------------
__global__ void conv_k(const float* __restrict__ in, unsigned short* __restrict__ out, long n)
{
    long i = ((long)blockIdx.x * blockDim.x + threadIdx.x) * 4;
    if (i >= n) return;
    float4 f = *(const float4*)&in[i];
    ushort4 o; o.x = f2bf(f.x); o.y = f2bf(f.y); o.z = f2bf(f.z); o.w = f2bf(f.w);
    *(ushort4*)&out[i] = o;
}

// all 15 weights in one launch: W[K][Mo] fp32 -> Wc[(k>>3)*Mo + m][8] bf16
struct WPack {
    const float* W[15];
    unsigned short* Wc[15];
    int K[15];
    int Mo[15];
};
__global__ void convW_all(WPack p)
{
    int wi = blockIdx.y;
    int i = blockIdx.x * blockDim.x + threadIdx.x;
    int K = p.K[wi], Mo = p.Mo[wi];
    if (i >= K * Mo) return;
    int k = i / Mo, m = i % Mo;
    p.Wc[wi][((long)(k >> 3) * Mo + m) * 8 + (k & 7)] = f2bf(p.W[wi][i]);
}

// XCD-grouping remap (bijective with pad): consecutive work items share an XCD L2.
__device__ __forceinline__ int xcd_work(int TOT) {
    int L = blockIdx.x;
    int per = (TOT + 7) >> 3;
    int wk = (L & 7) * per + (L >> 3);
    return (wk < TOT) ? wk : -1;
}

// ================= pipelined bf16 MFMA GEMM =================
// BM=128 BN=64 BK=64, 4 waves, double-buffered LDS (48KB), counted vmcnt.
// A = [U | V] bf16 row-major; Wc swizzled bf16.
// mode 0: outF/outB = acc+bias
// mode 1: outB = bf16( sigmoid(acc+bias) * HinF )          (r-gate)
// mode 2: outF = sigmoid(acc+bias)                          (z-gate -> Zf)
// mode 3: o = (1-Zf)*HinF + Zf*tanh(acc+bias); outF/outB    (GRU finish)
__global__ __launch_bounds__(256) void gemm_b(
    const unsigned short* __restrict__ U, int K1,
    const unsigned short* __restrict__ V, int K2,
    const unsigned short* __restrict__ Wc, const float* __restrict__ bias,
    float* __restrict__ outF, unsigned short* __restrict__ outB,
    const float* __restrict__ HinF, const float* __restrict__ Zf,
    int rows, int Mo, int mode)
{
    __shared__ __align__(16) unsigned short As[2][8][128][8];  // 32KB
    __shared__ __align__(16) unsigned short Bs[2][8][64][8];   // 16KB
    const int CB = Mo >> 6;
    const int RB = (rows + 127) >> 7;
    int wk = xcd_work(CB * RB);
    if (wk < 0) return;
    const int col0 = (wk % CB) * 64;
    const int row0 = (wk / CB) * 128;
    const int K = K1 + K2;
    const int nt = K >> 6;
    const int tid = threadIdx.x;
    const int l = tid & 63, w = tid >> 6;
    const int lm = l & 15, lg = l >> 4;
    f32x4 acc[2][4] = {};

    auto STAGE = [&](int buf, int t) {
        int k0 = t << 6;
#pragma unroll
        for (int i = 0; i < 4; ++i) {
            int c = i * 256 + tid;
            int m = c & 127, g = c >> 7;          // g wave-uniform
            int row = row0 + m; if (row >= rows) row = rows - 1;
            int k = k0 + g * 8;
            const unsigned short* sp = (k < K1) ? U + (long)row * K1 + k
                                                : V + (long)row * K2 + (k - K1);
            gll16(sp, &As[buf][0][0][0] + ((i * 256 + w * 64) << 3));
        }
#pragma unroll
        for (int j = 0; j < 2; ++j) {
            int c = j * 256 + tid;
            int n = c & 63, g = c >> 6;           // g wave-uniform
            gll16(Wc + ((long)((k0 >> 3) + g) * Mo + (col0 + n)) * 8,
                  &Bs[buf][0][0][0] + ((j * 256 + w * 64) << 3));
        }
    };

    STAGE(0, 0);                                   // prologue (6 loads/thread)
    for (int t = 0; t < nt; ++t) {
        const int cur = t & 1;
        if (t + 1 < nt) {
            STAGE(cur ^ 1, t + 1);                 // 6 more loads in flight
            asm volatile("s_waitcnt vmcnt(6)" ::: "memory");   // cur's loads done; next stays in flight
        } else {
            asm volatile("s_waitcnt vmcnt(0)" ::: "memory");
        }
        __builtin_amdgcn_s_barrier();
#pragma unroll
        for (int kk = 0; kk < 2; ++kk) {
            short8 a[2], b[4];
#pragma unroll
            for (int mi = 0; mi < 2; ++mi)
                a[mi] = *(const short8*)&As[cur][kk * 4 + lg][w * 32 + mi * 16 + lm][0];
#pragma unroll
            for (int ni = 0; ni < 4; ++ni)
                b[ni] = *(const short8*)&Bs[cur][kk * 4 + lg][ni * 16 + lm][0];
#pragma unroll
            for (int mi = 0; mi < 2; ++mi)
#pragma unroll
                for (int ni = 0; ni < 4; ++ni)
                    acc[mi][ni] = __builtin_amdgcn_mfma_f32_16x16x32_bf16(a[mi], b[ni], acc[mi][ni], 0, 0, 0);
        }
        __builtin_amdgcn_s_barrier();              // all reads of cur done before overwrite
    }

#pragma unroll
    for (int mi = 0; mi < 2; ++mi) {
        int rbase = row0 + w * 32 + mi * 16 + lg * 4;
#pragma unroll
        for (int r = 0; r < 4; ++r) {
            int row = rbase + r;
            if (row >= rows) continue;
#pragma unroll
            for (int ni = 0; ni < 4; ++ni) {
                int col = col0 + ni * 16 + lm;
                long idx = (long)row * Mo + col;
                float v = acc[mi][ni][r] + (bias ? bias[col] : 0.f);
                if (mode == 0) {
                    if (outF) outF[idx] = v;
                    if (outB) outB[idx] = f2bf(v);
                } else if (mode == 1) {
                    float rr = 1.f / (1.f + __expf(-v));
                    outB[idx] = f2bf(rr * HinF[idx]);
                } else if (mode == 2) {
                    outF[idx] = 1.f / (1.f + __expf(-v));
                } else {
                    float z  = Zf[idx];
                    float hh = tanhf(v);
                    float o  = (1.f - z) * HinF[idx] + z * hh;
                    if (outF) outF[idx] = o;
                    if (outB) outB[idx] = f2bf(o);
                }
            }
        }
    }
}

// ---------------- alpha (bf16 input) ----------------
__global__ void alpha_b(const unsigned short* __restrict__ XPb,
                        const float* __restrict__ a_s, const float* __restrict__ a_d,
                        float* __restrict__ AS, float* __restrict__ AD,
                        int Nn, int H, int C)
{
    int i = blockIdx.x * blockDim.x + threadIdx.x;
    if (i >= Nn * H) return;
    int n = i / H, h = i % H;
    const unsigned short* xp = &XPb[(long)n * H * C + (long)h * C];
    float ss = 0.f, sd = 0.f;
    for (int c = 0; c < C; ++c) {
        float v = bf2f(xp[c]);
        ss += v * a_s[h * C + c];
        sd += v * a_d[h * C + c];
    }
    AS[i] = ss; AD[i] = sd;
}

// ---------------- CSR build ----------------
__global__ void count_k(const int* __restrict__ dst, int E, int* __restrict__ cnt)
{
    int e = blockIdx.x * blockDim.x + threadIdx.x;
    if (e < E) atomicAdd(&cnt[dst[e]], 1);
}

__global__ __launch_bounds__(1024) void scan_k(const int* __restrict__ cnt, int Nn,
                                               int* __restrict__ off)
{
    __shared__ int part[1024];
    int tid = threadIdx.x;
    int chunk = (Nn + 1023) / 1024;
    int b = tid * chunk;
    int e = b + chunk; if (e > Nn) e = Nn; if (b > Nn) b = Nn;
    int s = 0;
    for (int i = b; i < e; ++i) s += cnt[i];
    part[tid] = s;
    __syncthreads();
    for (int d = 1; d < 1024; d <<= 1) {
        int v = (tid >= d) ? part[tid - d] : 0;
        __syncthreads();
        part[tid] += v;
        __syncthreads();
    }
    int run = tid ? part[tid - 1] : 0;
    for (int i = b; i < e; ++i) { off[i] = run; run += cnt[i]; }
    if (tid == 1023) off[Nn] = part[1023];
}

__global__ void scatter_k(const int* __restrict__ src, const int* __restrict__ dst, int E,
                          const int* __restrict__ off, int* __restrict__ cur,
                          int* __restrict__ csr_src)
{
    int e = blockIdx.x * blockDim.x + threadIdx.x;
    if (e < E) {
        int d = dst[e];
        int p = atomicAdd(&cur[d], 1);
        csr_src[off[d] + p] = src[e];
    }
}

// ---------------- bf16 GAT gather (8 feats/lane) ----------------
__global__ void gat_gather_b(const int* __restrict__ off, const int* __restrict__ csr_src,
                             const unsigned short* __restrict__ XPb,
                             const float* __restrict__ AS, const float* __restrict__ AD,
                             const float* __restrict__ bias,
                             unsigned short* __restrict__ Gout,
                             int Nn, int H, int C, int do_elu)
{
    const int D = H * C;
    const int lpn = D >> 3;
    const int npw = 64 / lpn;
    int lane = threadIdx.x & 63;
    long wave = ((long)blockIdx.x * blockDim.x + threadIdx.x) >> 6;
    int sub = lane / lpn;
    int cl = lane % lpn;
    long n = wave * npw + sub;
    if (n >= Nn) return;
    int j = cl * 8;
    int h = j / C;
    float ad = AD[n * H + h];
    float v = AS[n * H + h] + ad;
    v = v > 0.f ? v : NEG_SLOPE * v;
    float w = __expf(v);
    float den = w;
    float acc[8];
    {
        ushort8 xv = *(const ushort8*)&XPb[(long)n * D + j];
#pragma unroll
        for (int q = 0; q < 8; ++q) acc[q] = w * bf2f(xv[q]);
    }
    int b0 = off[n], b1 = off[n + 1];
    for (int i = b0; i < b1; ++i) {
        int s = csr_src[i];
        v = AS[s * H + h] + ad;
        v = v > 0.f ? v : NEG_SLOPE * v;
        w = __expf(v);
        den += w;
        ushort8 xv = *(const ushort8*)&XPb[(long)s * D + j];
#pragma unroll
        for (int q = 0; q < 8; ++q) acc[q] += w * bf2f(xv[q]);
    }
    float inv = 1.f / (den + 1e-16f);
    ushort8 ov;
#pragma unroll
    for (int q = 0; q < 8; ++q) {
        float o = acc[q] * inv + bias[j + q];
        if (do_elu) o = o > 0.f ? o : expm1f(o);
        ov[q] = f2bf(o);
    }
    *(ushort8*)&Gout[(long)n * D + j] = ov;
}

static inline int mfma_blocks(int rows, int Mo) {
    int TOT = (Mo >> 6) * ((rows + 127) >> 7);
    return ((TOT + 7) / 8) * 8;
}

static inline void launch_gather(const int* ioff, const int* csr,
                                 const unsigned short* xp, const float* AS, const float* AD,
                                 const float* bias, unsigned short* gout,
                                 int Nn, int H, int C, int elu, hipStream_t stream)
{
    int D = H * C;
    int lpn = D >> 3;
    int npw = 64 / lpn;
    long waves = (Nn + npw - 1) / npw;
    int blocks = (int)((waves * 64 + 255) / 256);
    gat_gather_b<<<blocks, 256, 0, stream>>>(ioff, csr, xp, AS, AD, bias, gout, Nn, H, C, elu);
}

extern "C" void kernel_launch(void* const* d_in, const int* in_sizes, int n_in,
                              void* d_out, int out_size, void* d_ws, size_t ws_size,
                              hipStream_t stream)
{
    const float* x    = (const float*)d_in[0];
    const int*   ei   = (const int*)  d_in[1];
    const float* W_tr = (const float*)d_in[2];
    const float* b_tr = (const float*)d_in[3];
    const float* W1   = (const float*)d_in[4];
    const float* as1  = (const float*)d_in[5];
    const float* ad1  = (const float*)d_in[6];
    const float* b1   = (const float*)d_in[7];
    const float* Wr1  = (const float*)d_in[8];
    const float* br1  = (const float*)d_in[9];
    const float* Wz1  = (const float*)d_in[10];
    const float* bz1  = (const float*)d_in[11];
    const float* Wh1  = (const float*)d_in[12];
    const float* bh1  = (const float*)d_in[13];
    const float* Wp2  = (const float*)d_in[14];
    const float* bp2  = (const float*)d_in[15];
    const float* W2   = (const float*)d_in[16];
    const float* as2  = (const float*)d_in[17];
    const float* ad2  = (const float*)d_in[18];
    const float* b2   = (const float*)d_in[19];
    const float* Wr2  = (const float*)d_in[20];
    const float* br2  = (const float*)d_in[21];
    const float* Wz2  = (const float*)d_in[22];
    const float* bz2  = (const float*)d_in[23];
    const float* Wh2  = (const float*)d_in[24];
    const float* bh2  = (const float*)d_in[25];
    const float* Wp3  = (const float*)d_in[26];
    const float* bp3  = (const float*)d_in[27];
    const float* W3   = (const float*)d_in[28];
    const float* as3  = (const float*)d_in[29];
    const float* ad3  = (const float*)d_in[30];
    const float* b3   = (const float*)d_in[31];
    const float* Wr3  = (const float*)d_in[32];
    const float* br3  = (const float*)d_in[33];
    const float* Wz3  = (const float*)d_in[34];
    const float* bz3  = (const float*)d_in[35];
    const float* Wh3  = (const float*)d_in[36];
    const float* bh3  = (const float*)d_in[37];

    const int Nn = in_sizes[0] / 128;   // 50000
    const int E  = in_sizes[1] / 2;     // 800000
    const int* srcp = ei;
    const int* dstp = ei + E;

    // ---------------- workspace layout ----------------
    float* X0f  = (float*)d_ws;                         // [N,256] fp32 (L1 hin)
    float* HINf = X0f  + (size_t)Nn * 256;              // [N,128] fp32 (L2 hin; L3: H3f [N,64])
    float* Zf   = HINf + (size_t)Nn * 128;              // [N,256] fp32 (z-gate, all layers)
    float* AS   = Zf   + (size_t)Nn * 256;              // [N,8]
    float* AD   = AS   + (size_t)Nn * 8;                // [N,8]
    unsigned short* X0b  = (unsigned short*)(AD + (size_t)Nn * 8); // [N,256] (L2: xp2; L3: CX2b)
    unsigned short* XPb  = X0b + (size_t)Nn * 256;      // [N,256] (L1 xp; then x1)
    unsigned short* Gb   = XPb + (size_t)Nn * 256;      // [N,256] (gathers; also xb at start)
    unsigned short* RHb  = Gb  + (size_t)Nn * 256;      // [N,256] (r outputs)
    unsigned short* HINb = RHb + (size_t)Nn * 256;      // [N,128] (L2 hinb; L3: H3b + XP3b)
    unsigned short* wpool = HINb + (size_t)Nn * 128;
    unsigned short* Wtrc = wpool;                       // 128*256
    unsigned short* W1c  = Wtrc + 128 * 256;            // 256*256
    unsigned short* Wr1c = W1c  + 256 * 256;            // 512*256
    unsigned short* Wz1c = Wr1c + 512 * 256;
    unsigned short* Wh1c = Wz1c + 512 * 256;
    unsigned short* Wp2c = Wh1c + 512 * 256;            // 256*128
    unsigned short* W2c  = Wp2c + 256 * 128;
    unsigned short* Wr2c = W2c  + 256 * 128;
    unsigned short* Wz2c = Wr2c + 256 * 128;
    unsigned short* Wh2c = Wz2c + 256 * 128;
    unsigned short* Wp3c = Wh2c + 256 * 128;            // 128*64
    unsigned short* W3c  = Wp3c + 128 * 64;
    unsigned short* Wr3c = W3c  + 128 * 64;
    unsigned short* Wz3c = Wr3c + 128 * 64;
    unsigned short* Wh3c = Wz3c + 128 * 64;
    int* ioff = (int*)(((size_t)(Wh3c + 128 * 64) + 15) & ~(size_t)15);
    int* cnt  = ioff + (Nn + 1);
    int* cur  = cnt + Nn;
    int* csr  = cur + Nn;

    dim3 blk(256);

    // ---------- all 15 weight conversions in ONE launch ----------
    {
        WPack p;
        const float* Ws[15]     = {W_tr, W1, Wr1, Wz1, Wh1, Wp2, W2, Wr2, Wz2, Wh2,
                                   Wp3, W3, Wr3, Wz3, Wh3};
        unsigned short* Wcs[15] = {Wtrc, W1c, Wr1c, Wz1c, Wh1c, Wp2c, W2c, Wr2c, Wz2c, Wh2c,
                                   Wp3c, W3c, Wr3c, Wz3c, Wh3c};
        int Ks[15]              = {128, 256, 512, 512, 512, 256, 256, 256, 256, 256,
                                   128, 128, 128, 128, 128};
        int Mos[15]             = {256, 256, 256, 256, 256, 128, 128, 128, 128, 128,
                                   64, 64, 64, 64, 64};
        for (int i = 0; i < 15; ++i) { p.W[i] = Ws[i]; p.Wc[i] = Wcs[i]; p.K[i] = Ks[i]; p.Mo[i] = Mos[i]; }
        convW_all<<<dim3((512 * 256 + 255) / 256, 15), blk, 0, stream>>>(p);
    }

    // ---------- CSR build ----------
    hipMemsetAsync(cnt, 0, (size_t)Nn * 4, stream);
    hipMemsetAsync(cur, 0, (size_t)Nn * 4, stream);
    count_k<<<(E + 255) / 256, blk, 0, stream>>>(dstp, E, cnt);
    scan_k<<<1, 1024, 0, stream>>>(cnt, Nn, ioff);
    scatter_k<<<(E + 255) / 256, blk, 0, stream>>>(srcp, dstp, E, ioff, cur, csr);

    // ---------- stage 0: X0 = x @ W_tr + b_tr ----------
    unsigned short* xb = Gb;   // Gb free until gather1
    conv_k<<<(int)(((long)Nn * 128 / 4 + 255) / 256), blk, 0, stream>>>(x, xb, (long)Nn * 128);
    gemm_b<<<mfma_blocks(Nn, 256), blk, 0, stream>>>(xb, 128, nullptr, 0, Wtrc, b_tr, X0f, X0b, nullptr, nullptr, Nn, 256, 0);

    // ================= layer 1 (D=256, H=8, C=32) =================
    gemm_b<<<mfma_blocks(Nn, 256), blk, 0, stream>>>(X0b, 256, nullptr, 0, W1c, nullptr, nullptr, XPb, nullptr, nullptr, Nn, 256, 0);
    alpha_b<<<(Nn * 8 + 255) / 256, blk, 0, stream>>>(XPb, as1, ad1, AS, AD, Nn, 8, 32);
    launch_gather(ioff, csr, XPb, AS, AD, b1, Gb, Nn, 8, 32, 1, stream);
    gemm_b<<<mfma_blocks(Nn, 256), blk, 0, stream>>>(Gb, 256, X0b, 256, Wr1c, br1, nullptr, RHb, X0f, nullptr, Nn, 256, 1);
    gemm_b<<<mfma_blocks(Nn, 256), blk, 0, stream>>>(Gb, 256, X0b, 256, Wz1c, bz1, Zf, nullptr, nullptr, nullptr, Nn, 256, 2);
    gemm_b<<<mfma_blocks(Nn, 256), blk, 0, stream>>>(Gb, 256, RHb, 256, Wh1c, bh1, nullptr, XPb, X0f, Zf, Nn, 256, 3);
    // XPb holds x1 (bf16)

    // ================= layer 2 (D=128, H=4, C=32) =================
    gemm_b<<<mfma_blocks(Nn, 128), blk, 0, stream>>>(XPb, 256, nullptr, 0, Wp2c, bp2, HINf, HINb, nullptr, nullptr, Nn, 128, 0);
    gemm_b<<<mfma_blocks(Nn, 128), blk, 0, stream>>>(XPb, 256, nullptr, 0, W2c, nullptr, nullptr, X0b, nullptr, nullptr, Nn, 128, 0);
    alpha_b<<<(Nn * 4 + 255) / 256, blk, 0, stream>>>(X0b, as2, ad2, AS, AD, Nn, 4, 32);
    launch_gather(ioff, csr, X0b, AS, AD, b2, Gb, Nn, 4, 32, 1, stream);
    gemm_b<<<mfma_blocks(Nn, 128), blk, 0, stream>>>(Gb, 128, HINb, 128, Wr2c, br2, nullptr, RHb, HINf, nullptr, Nn, 128, 1);
    gemm_b<<<mfma_blocks(Nn, 128), blk, 0, stream>>>(Gb, 128, HINb, 128, Wz2c, bz2, Zf, nullptr, nullptr, nullptr, Nn, 128, 2);
    gemm_b<<<mfma_blocks(Nn, 128), blk, 0, stream>>>(Gb, 128, RHb, 128, Wh2c, bh2, nullptr, X0b, HINf, Zf, Nn, 128, 3);
    // X0b holds x2 (bf16)

    // ================= layer 3 (D=64, H=1, C=64) =================
    unsigned short* H3b  = HINb;                 // [N,64]
    unsigned short* XP3b = HINb + (size_t)Nn * 64;
    gemm_b<<<mfma_blocks(Nn, 64), blk, 0, stream>>>(X0b, 128, nullptr, 0, Wp3c, bp3, HINf, H3b, nullptr, nullptr, Nn, 64, 0);
    gemm_b<<<mfma_blocks(Nn, 64), blk, 0, stream>>>(X0b, 128, nullptr, 0, W3c, nullptr, nullptr, XP3b, nullptr, nullptr, Nn, 64, 0);
    alpha_b<<<(Nn + 255) / 256, blk, 0, stream>>>(XP3b, as3, ad3, AS, AD, Nn, 1, 64);
    launch_gather(ioff, csr, XP3b, AS, AD, b3, Gb, Nn, 1, 64, 0, stream);
    gemm_b<<<mfma_blocks(Nn, 64), blk, 0, stream>>>(Gb, 64, H3b, 64, Wr3c, br3, nullptr, RHb, HINf, nullptr, Nn, 64, 1);
    gemm_b<<<mfma_blocks(Nn, 64), blk, 0, stream>>>(Gb, 64, H3b, 64, Wz3c, bz3, Zf, nullptr, nullptr, nullptr, Nn, 64, 2);
    gemm_b<<<mfma_blocks(Nn, 64), blk, 0, stream>>>(Gb, 64, RHb, 64, Wh3c, bh3, (float*)d_out, nullptr, HINf, Zf, Nn, 64, 3);
}

// Round 8
// 832.560 us; speedup vs baseline: 1.2050x; 1.2050x over previous
//
#include <hip/hip_runtime.h>

#define NEG_SLOPE 0.2f

typedef __attribute__((ext_vector_type(8))) short short8;
typedef __attribute__((ext_vector_type(8))) unsigned short ushort8;
typedef __attribute__((ext_vector_type(4))) float f32x4;

__device__ __forceinline__ unsigned short f2bf(float f) {
    unsigned int u = __float_as_uint(f);
    u += 0x7fff + ((u >> 16) & 1);     // round-to-nearest-even
    return (unsigned short)(u >> 16);
}
__device__ __forceinline__ float bf2f(unsigned short s) {
    return __uint_as_float(((unsigned int)s) << 16);
}

// async global->LDS, 16B per lane; lds base must be wave-uniform
__device__ __forceinline__ void gll16(const void* g, void* l) {
    __builtin_amdgcn_global_load_lds(
        (const __attribute__((address_space(1))) void*)g,
        (__attribute__((address_space(3))) void*)l, 16, 0, 0);
}

// ---------------- converters ----------------
__global__ void conv_k(const float* __restrict__ in, unsigned short* __restrict__ out, long n)
{
    long i = ((long)blockIdx.x * blockDim.x + threadIdx.x) * 4;
    if (i >= n) return;
    float4 f = *(const float4*)&in[i];
    ushort4 o; o.x = f2bf(f.x); o.y = f2bf(f.y); o.z = f2bf(f.z); o.w = f2bf(f.w);
    *(ushort4*)&out[i] = o;
}

// all 15 weights in one launch: W[K][Mo] fp32 -> Wc[(k>>3)*Mo + m][8] bf16
struct WPack {
    const float* W[15];
    unsigned short* Wc[15];
    int K[15];
    int Mo[15];
};
__global__ void convW_all(WPack p)
{
    int wi = blockIdx.y;
    int i = blockIdx.x * blockDim.x + threadIdx.x;
    int K = p.K[wi], Mo = p.Mo[wi];
    if (i >= K * Mo) return;
    int k = i / Mo, m = i % Mo;
    p.Wc[wi][((long)(k >> 3) * Mo + m) * 8 + (k & 7)] = f2bf(p.W[wi][i]);
}

// XCD-grouping remap (bijective with pad): consecutive work items share an XCD L2.
__device__ __forceinline__ int xcd_work(int TOT) {
    int L = blockIdx.x;
    int per = (TOT + 7) >> 3;
    int wk = (L & 7) * per + (L >> 3);
    return (wk < TOT) ? wk : -1;
}

// ================= bf16 MFMA GEMM, 64x64 wave tile =================
// NI=8: BN=128, 4 waves in 2x2, wave tile 64x64 (4x4 frags).
// NI=4: BN=64,  4 waves in 4x1, wave tile 32x64 (2x4 frags).
// BM=128, BK=64, single-buffer LDS, __syncthreads barriers (r6-proven staging).
// mode 0: outF/outB = acc+bias (either may be null)
// mode 3: o = (1-Zf)*HinF + Zf*tanh(acc+bias); outF/outB (GRU finish)
template<int NI, int MODE>
__global__ __launch_bounds__(256) void gemm_t(
    const unsigned short* __restrict__ U, int K1,
    const unsigned short* __restrict__ V, int K2,
    const unsigned short* __restrict__ Wc, const float* __restrict__ bias,
    float* __restrict__ outF, unsigned short* __restrict__ outB,
    const float* __restrict__ HinF, const float* __restrict__ Zf,
    int rows, int Mo)
{
    constexpr int BN = NI * 16;
    constexpr int MI = (NI == 8) ? 4 : 2;
    __shared__ __align__(16) unsigned short As[8][128][8];     // 16KB
    __shared__ __align__(16) unsigned short Bs[8][BN][8];      // 16KB (NI=8) / 8KB
    const int CB = Mo / BN;
    const int RB = (rows + 127) >> 7;
    int wk = xcd_work(CB * RB);
    if (wk < 0) return;
    const int col0 = (wk % CB) * BN;
    const int row0 = (wk / CB) * 128;
    const int K = K1 + K2;
    const int tid = threadIdx.x;
    const int l = tid & 63, w = tid >> 6;
    const int lm = l & 15, lg = l >> 4;
    const int wrow = (NI == 8) ? (w >> 1) * 64 : w * 32;
    const int wcol = (NI == 8) ? (w & 1) * 64 : 0;
    f32x4 acc[MI][4] = {};

    for (int k0 = 0; k0 < K; k0 += 64) {
#pragma unroll
        for (int i = 0; i < 4; ++i) {
            int c = i * 256 + tid;
            int m = c & 127, g = c >> 7;          // g wave-uniform
            int row = row0 + m; if (row >= rows) row = rows - 1;
            int k = k0 + g * 8;
            const unsigned short* sp = (k < K1) ? U + (long)row * K1 + k
                                                : V + (long)row * K2 + (k - K1);
            gll16(sp, &As[0][0][0] + ((i * 256 + w * 64) << 3));
        }
#pragma unroll
        for (int j = 0; j < NI / 2; ++j) {
            int c = j * 256 + tid;
            int n = c & (BN - 1), g = c / BN;     // g wave-uniform (BN>=64)
            gll16(Wc + ((long)((k0 >> 3) + g) * Mo + (col0 + n)) * 8,
                  &Bs[0][0][0] + ((j * 256 + w * 64) << 3));
        }
        __syncthreads();
#pragma unroll
        for (int kk = 0; kk < 2; ++kk) {
            short8 a[MI], b[4];
#pragma unroll
            for (int mi = 0; mi < MI; ++mi)
                a[mi] = *(const short8*)&As[kk * 4 + lg][wrow + mi * 16 + lm][0];
#pragma unroll
            for (int ni = 0; ni < 4; ++ni)
                b[ni] = *(const short8*)&Bs[kk * 4 + lg][wcol + ni * 16 + lm][0];
#pragma unroll
            for (int mi = 0; mi < MI; ++mi)
#pragma unroll
                for (int ni = 0; ni < 4; ++ni)
                    acc[mi][ni] = __builtin_amdgcn_mfma_f32_16x16x32_bf16(a[mi], b[ni], acc[mi][ni], 0, 0, 0);
        }
        __syncthreads();
    }

#pragma unroll
    for (int mi = 0; mi < MI; ++mi) {
        int rbase = row0 + wrow + mi * 16 + lg * 4;
#pragma unroll
        for (int r = 0; r < 4; ++r) {
            int row = rbase + r;
            if (row >= rows) continue;
#pragma unroll
            for (int ni = 0; ni < 4; ++ni) {
                int col = col0 + wcol + ni * 16 + lm;
                long idx = (long)row * Mo + col;
                float v = acc[mi][ni][r] + (bias ? bias[col] : 0.f);
                if (MODE == 0) {
                    if (outF) outF[idx] = v;
                    if (outB) outB[idx] = f2bf(v);
                } else {
                    float z  = Zf[idx];
                    float hh = tanhf(v);
                    float o  = (1.f - z) * HinF[idx] + z * hh;
                    if (outF) outF[idx] = o;
                    if (outB) outB[idx] = f2bf(o);
                }
            }
        }
    }
}

// ================= fused r+z dual-B GEMM (shared A = [G | Hin]) =================
// BM=128, BN=64, BK=64, wave tile 32x64 per matrix; outputs:
//   RHb = bf16( sigmoid(acc_r + br) * HinF ),  Zf = sigmoid(acc_z + bz)
__global__ __launch_bounds__(256) void gemm_rz(
    const unsigned short* __restrict__ U, int K1,
    const unsigned short* __restrict__ V, int K2,
    const unsigned short* __restrict__ Wrc, const unsigned short* __restrict__ Wzc,
    const float* __restrict__ br, const float* __restrict__ bz,
    const float* __restrict__ HinF,
    unsigned short* __restrict__ RHb, float* __restrict__ Zf,
    int rows, int Mo)
{
    __shared__ __align__(16) unsigned short As[8][128][8];   // 16KB
    __shared__ __align__(16) unsigned short Br[8][64][8];    //  8KB
    __shared__ __align__(16) unsigned short Bz[8][64][8];    //  8KB
    const int CB = Mo >> 6;
    const int RB = (rows + 127) >> 7;
    int wk = xcd_work(CB * RB);
    if (wk < 0) return;
    const int col0 = (wk % CB) * 64;
    const int row0 = (wk / CB) * 128;
    const int K = K1 + K2;
    const int tid = threadIdx.x;
    const int l = tid & 63, w = tid >> 6;
    const int lm = l & 15, lg = l >> 4;
    f32x4 accr[2][4] = {}, accz[2][4] = {};

    for (int k0 = 0; k0 < K; k0 += 64) {
#pragma unroll
        for (int i = 0; i < 4; ++i) {
            int c = i * 256 + tid;
            int m = c & 127, g = c >> 7;
            int row = row0 + m; if (row >= rows) row = rows - 1;
            int k = k0 + g * 8;
            const unsigned short* sp = (k < K1) ? U + (long)row * K1 + k
                                                : V + (long)row * K2 + (k - K1);
            gll16(sp, &As[0][0][0] + ((i * 256 + w * 64) << 3));
        }
#pragma unroll
        for (int j = 0; j < 2; ++j) {
            int c = j * 256 + tid;
            int n = c & 63, g = c >> 6;
            long base = ((long)((k0 >> 3) + g) * Mo + (col0 + n)) * 8;
            gll16(Wrc + base, &Br[0][0][0] + ((j * 256 + w * 64) << 3));
            gll16(Wzc + base, &Bz[0][0][0] + ((j * 256 + w * 64) << 3));
        }
        __syncthreads();
#pragma unroll
        for (int kk = 0; kk < 2; ++kk) {
            short8 a[2], brv[4], bzv[4];
#pragma unroll
            for (int mi = 0; mi < 2; ++mi)
                a[mi] = *(const short8*)&As[kk * 4 + lg][w * 32 + mi * 16 + lm][0];
#pragma unroll
            for (int ni = 0; ni < 4; ++ni) {
                brv[ni] = *(const short8*)&Br[kk * 4 + lg][ni * 16 + lm][0];
                bzv[ni] = *(const short8*)&Bz[kk * 4 + lg][ni * 16 + lm][0];
            }
#pragma unroll
            for (int mi = 0; mi < 2; ++mi)
#pragma unroll
                for (int ni = 0; ni < 4; ++ni) {
                    accr[mi][ni] = __builtin_amdgcn_mfma_f32_16x16x32_bf16(a[mi], brv[ni], accr[mi][ni], 0, 0, 0);
                    accz[mi][ni] = __builtin_amdgcn_mfma_f32_16x16x32_bf16(a[mi], bzv[ni], accz[mi][ni], 0, 0, 0);
                }
        }
        __syncthreads();
    }

#pragma unroll
    for (int mi = 0; mi < 2; ++mi) {
        int rbase = row0 + w * 32 + mi * 16 + lg * 4;
#pragma unroll
        for (int r = 0; r < 4; ++r) {
            int row = rbase + r;
            if (row >= rows) continue;
#pragma unroll
            for (int ni = 0; ni < 4; ++ni) {
                int col = col0 + ni * 16 + lm;
                long idx = (long)row * Mo + col;
                float rv = 1.f / (1.f + __expf(-(accr[mi][ni][r] + br[col])));
                float zv = 1.f / (1.f + __expf(-(accz[mi][ni][r] + bz[col])));
                RHb[idx] = f2bf(rv * HinF[idx]);
                Zf[idx] = zv;
            }
        }
    }
}

// ---------------- alpha (bf16 input) ----------------
__global__ void alpha_b(const unsigned short* __restrict__ XPb,
                        const float* __restrict__ a_s, const float* __restrict__ a_d,
                        float* __restrict__ AS, float* __restrict__ AD,
                        int Nn, int H, int C)
{
    int i = blockIdx.x * blockDim.x + threadIdx.x;
    if (i >= Nn * H) return;
    int n = i / H, h = i % H;
    const unsigned short* xp = &XPb[(long)n * H * C + (long)h * C];
    float ss = 0.f, sd = 0.f;
    for (int c = 0; c < C; ++c) {
        float v = bf2f(xp[c]);
        ss += v * a_s[h * C + c];
        sd += v * a_d[h * C + c];
    }
    AS[i] = ss; AD[i] = sd;
}

// ---------------- CSR build ----------------
__global__ void count_k(const int* __restrict__ dst, int E, int* __restrict__ cnt)
{
    int e = blockIdx.x * blockDim.x + threadIdx.x;
    if (e < E) atomicAdd(&cnt[dst[e]], 1);
}

__global__ __launch_bounds__(1024) void scan_k(const int* __restrict__ cnt, int Nn,
                                               int* __restrict__ off)
{
    __shared__ int part[1024];
    int tid = threadIdx.x;
    int chunk = (Nn + 1023) / 1024;
    int b = tid * chunk;
    int e = b + chunk; if (e > Nn) e = Nn; if (b > Nn) b = Nn;
    int s = 0;
    for (int i = b; i < e; ++i) s += cnt[i];
    part[tid] = s;
    __syncthreads();
    for (int d = 1; d < 1024; d <<= 1) {
        int v = (tid >= d) ? part[tid - d] : 0;
        __syncthreads();
        part[tid] += v;
        __syncthreads();
    }
    int run = tid ? part[tid - 1] : 0;
    for (int i = b; i < e; ++i) { off[i] = run; run += cnt[i]; }
    if (tid == 1023) off[Nn] = part[1023];
}

__global__ void scatter_k(const int* __restrict__ src, const int* __restrict__ dst, int E,
                          const int* __restrict__ off, int* __restrict__ cur,
                          int* __restrict__ csr_src)
{
    int e = blockIdx.x * blockDim.x + threadIdx.x;
    if (e < E) {
        int d = dst[e];
        int p = atomicAdd(&cur[d], 1);
        csr_src[off[d] + p] = src[e];
    }
}

// ---------------- bf16 GAT gather (8 feats/lane) ----------------
__global__ void gat_gather_b(const int* __restrict__ off, const int* __restrict__ csr_src,
                             const unsigned short* __restrict__ XPb,
                             const float* __restrict__ AS, const float* __restrict__ AD,
                             const float* __restrict__ bias,
                             unsigned short* __restrict__ Gout,
                             int Nn, int H, int C, int do_elu)
{
    const int D = H * C;
    const int lpn = D >> 3;
    const int npw = 64 / lpn;
    int lane = threadIdx.x & 63;
    long wave = ((long)blockIdx.x * blockDim.x + threadIdx.x) >> 6;
    int sub = lane / lpn;
    int cl = lane % lpn;
    long n = wave * npw + sub;
    if (n >= Nn) return;
    int j = cl * 8;
    int h = j / C;
    float ad = AD[n * H + h];
    float v = AS[n * H + h] + ad;
    v = v > 0.f ? v : NEG_SLOPE * v;
    float w = __expf(v);
    float den = w;
    float acc[8];
    {
        ushort8 xv = *(const ushort8*)&XPb[(long)n * D + j];
#pragma unroll
        for (int q = 0; q < 8; ++q) acc[q] = w * bf2f(xv[q]);
    }
    int b0 = off[n], b1 = off[n + 1];
    for (int i = b0; i < b1; ++i) {
        int s = csr_src[i];
        v = AS[s * H + h] + ad;
        v = v > 0.f ? v : NEG_SLOPE * v;
        w = __expf(v);
        den += w;
        ushort8 xv = *(const ushort8*)&XPb[(long)s * D + j];
#pragma unroll
        for (int q = 0; q < 8; ++q) acc[q] += w * bf2f(xv[q]);
    }
    float inv = 1.f / (den + 1e-16f);
    ushort8 ov;
#pragma unroll
    for (int q = 0; q < 8; ++q) {
        float o = acc[q] * inv + bias[j + q];
        if (do_elu) o = o > 0.f ? o : expm1f(o);
        ov[q] = f2bf(o);
    }
    *(ushort8*)&Gout[(long)n * D + j] = ov;
}

static inline int pad8(int t) { return ((t + 7) / 8) * 8; }

static inline void launch_gather(const int* ioff, const int* csr,
                                 const unsigned short* xp, const float* AS, const float* AD,
                                 const float* bias, unsigned short* gout,
                                 int Nn, int H, int C, int elu, hipStream_t stream)
{
    int D = H * C;
    int lpn = D >> 3;
    int npw = 64 / lpn;
    long waves = (Nn + npw - 1) / npw;
    int blocks = (int)((waves * 64 + 255) / 256);
    gat_gather_b<<<blocks, 256, 0, stream>>>(ioff, csr, xp, AS, AD, bias, gout, Nn, H, C, elu);
}

extern "C" void kernel_launch(void* const* d_in, const int* in_sizes, int n_in,
                              void* d_out, int out_size, void* d_ws, size_t ws_size,
                              hipStream_t stream)
{
    const float* x    = (const float*)d_in[0];
    const int*   ei   = (const int*)  d_in[1];
    const float* W_tr = (const float*)d_in[2];
    const float* b_tr = (const float*)d_in[3];
    const float* W1   = (const float*)d_in[4];
    const float* as1  = (const float*)d_in[5];
    const float* ad1  = (const float*)d_in[6];
    const float* b1   = (const float*)d_in[7];
    const float* Wr1  = (const float*)d_in[8];
    const float* br1  = (const float*)d_in[9];
    const float* Wz1  = (const float*)d_in[10];
    const float* bz1  = (const float*)d_in[11];
    const float* Wh1  = (const float*)d_in[12];
    const float* bh1  = (const float*)d_in[13];
    const float* Wp2  = (const float*)d_in[14];
    const float* bp2  = (const float*)d_in[15];
    const float* W2   = (const float*)d_in[16];
    const float* as2  = (const float*)d_in[17];
    const float* ad2  = (const float*)d_in[18];
    const float* b2   = (const float*)d_in[19];
    const float* Wr2  = (const float*)d_in[20];
    const float* br2  = (const float*)d_in[21];
    const float* Wz2  = (const float*)d_in[22];
    const float* bz2  = (const float*)d_in[23];
    const float* Wh2  = (const float*)d_in[24];
    const float* bh2  = (const float*)d_in[25];
    const float* Wp3  = (const float*)d_in[26];
    const float* bp3  = (const float*)d_in[27];
    const float* W3   = (const float*)d_in[28];
    const float* as3  = (const float*)d_in[29];
    const float* ad3  = (const float*)d_in[30];
    const float* b3   = (const float*)d_in[31];
    const float* Wr3  = (const float*)d_in[32];
    const float* br3  = (const float*)d_in[33];
    const float* Wz3  = (const float*)d_in[34];
    const float* bz3  = (const float*)d_in[35];
    const float* Wh3  = (const float*)d_in[36];
    const float* bh3  = (const float*)d_in[37];

    const int Nn = in_sizes[0] / 128;   // 50000
    const int E  = in_sizes[1] / 2;     // 800000
    const int* srcp = ei;
    const int* dstp = ei + E;

    // ---------------- workspace layout ----------------
    float* X0f  = (float*)d_ws;                         // [N,256] fp32 (L1 hin)
    float* HINf = X0f  + (size_t)Nn * 256;              // [N,128] fp32 (L2 hin; L3 [N,64])
    float* Zf   = HINf + (size_t)Nn * 128;              // [N,256] fp32 (z-gate)
    float* AS   = Zf   + (size_t)Nn * 256;              // [N,8]
    float* AD   = AS   + (size_t)Nn * 8;                // [N,8]
    unsigned short* X0b  = (unsigned short*)(AD + (size_t)Nn * 8); // [N,256]
    unsigned short* XPb  = X0b + (size_t)Nn * 256;      // [N,256]
    unsigned short* Gb   = XPb + (size_t)Nn * 256;      // [N,256]
    unsigned short* RHb  = Gb  + (size_t)Nn * 256;      // [N,256]
    unsigned short* HINb = RHb + (size_t)Nn * 256;      // [N,128]
    unsigned short* wpool = HINb + (size_t)Nn * 128;
    unsigned short* Wtrc = wpool;                       // 128*256
    unsigned short* W1c  = Wtrc + 128 * 256;            // 256*256
    unsigned short* Wr1c = W1c  + 256 * 256;            // 512*256
    unsigned short* Wz1c = Wr1c + 512 * 256;
    unsigned short* Wh1c = Wz1c + 512 * 256;
    unsigned short* Wp2c = Wh1c + 512 * 256;            // 256*128
    unsigned short* W2c  = Wp2c + 256 * 128;
    unsigned short* Wr2c = W2c  + 256 * 128;
    unsigned short* Wz2c = Wr2c + 256 * 128;
    unsigned short* Wh2c = Wz2c + 256 * 128;
    unsigned short* Wp3c = Wh2c + 256 * 128;            // 128*64
    unsigned short* W3c  = Wp3c + 128 * 64;
    unsigned short* Wr3c = W3c  + 128 * 64;
    unsigned short* Wz3c = Wr3c + 128 * 64;
    unsigned short* Wh3c = Wz3c + 128 * 64;
    int* ioff = (int*)(((size_t)(Wh3c + 128 * 64) + 15) & ~(size_t)15);
    int* cnt  = ioff + (Nn + 1);
    int* cur  = cnt + Nn;
    int* csr  = cur + Nn;

    dim3 blk(256);
    const int RB = (Nn + 127) >> 7;     // 391
    int g128_256 = pad8((256 / 128) * RB);  // BN=128, Mo=256
    int g128_128 = pad8((128 / 128) * RB);  // BN=128, Mo=128
    int g64_64   = pad8((64 / 64) * RB);    // BN=64,  Mo=64
    int grz_256  = pad8((256 / 64) * RB);
    int grz_128  = pad8((128 / 64) * RB);
    int grz_64   = pad8((64 / 64) * RB);

    // ---------- all 15 weight conversions in ONE launch ----------
    {
        WPack p;
        const float* Ws[15]     = {W_tr, W1, Wr1, Wz1, Wh1, Wp2, W2, Wr2, Wz2, Wh2,
                                   Wp3, W3, Wr3, Wz3, Wh3};
        unsigned short* Wcs[15] = {Wtrc, W1c, Wr1c, Wz1c, Wh1c, Wp2c, W2c, Wr2c, Wz2c, Wh2c,
                                   Wp3c, W3c, Wr3c, Wz3c, Wh3c};
        int Ks[15]              = {128, 256, 512, 512, 512, 256, 256, 256, 256, 256,
                                   128, 128, 128, 128, 128};
        int Mos[15]             = {256, 256, 256, 256, 256, 128, 128, 128, 128, 128,
                                   64, 64, 64, 64, 64};
        for (int i = 0; i < 15; ++i) { p.W[i] = Ws[i]; p.Wc[i] = Wcs[i]; p.K[i] = Ks[i]; p.Mo[i] = Mos[i]; }
        convW_all<<<dim3((512 * 256 + 255) / 256, 15), blk, 0, stream>>>(p);
    }

    // ---------- CSR build ----------
    hipMemsetAsync(cnt, 0, (size_t)Nn * 4, stream);
    hipMemsetAsync(cur, 0, (size_t)Nn * 4, stream);
    count_k<<<(E + 255) / 256, blk, 0, stream>>>(dstp, E, cnt);
    scan_k<<<1, 1024, 0, stream>>>(cnt, Nn, ioff);
    scatter_k<<<(E + 255) / 256, blk, 0, stream>>>(srcp, dstp, E, ioff, cur, csr);

    // ---------- stage 0: X0 = x @ W_tr + b_tr (dual write) ----------
    unsigned short* xb = Gb;   // Gb free until gather1
    conv_k<<<(int)(((long)Nn * 128 / 4 + 255) / 256), blk, 0, stream>>>(x, xb, (long)Nn * 128);
    gemm_t<8,0><<<g128_256, blk, 0, stream>>>(xb, 128, nullptr, 0, Wtrc, b_tr, X0f, X0b, nullptr, nullptr, Nn, 256);

    // ================= layer 1 (D=256, H=8, C=32) =================
    gemm_t<8,0><<<g128_256, blk, 0, stream>>>(X0b, 256, nullptr, 0, W1c, nullptr, nullptr, XPb, nullptr, nullptr, Nn, 256);
    alpha_b<<<(Nn * 8 + 255) / 256, blk, 0, stream>>>(XPb, as1, ad1, AS, AD, Nn, 8, 32);
    launch_gather(ioff, csr, XPb, AS, AD, b1, Gb, Nn, 8, 32, 1, stream);
    gemm_rz<<<grz_256, blk, 0, stream>>>(Gb, 256, X0b, 256, Wr1c, Wz1c, br1, bz1, X0f, RHb, Zf, Nn, 256);
    gemm_t<8,3><<<g128_256, blk, 0, stream>>>(Gb, 256, RHb, 256, Wh1c, bh1, nullptr, XPb, X0f, Zf, Nn, 256);
    // XPb holds x1 (bf16)

    // ================= layer 2 (D=128, H=4, C=32) =================
    gemm_t<8,0><<<g128_128, blk, 0, stream>>>(XPb, 256, nullptr, 0, Wp2c, bp2, HINf, HINb, nullptr, nullptr, Nn, 128);
    gemm_t<8,0><<<g128_128, blk, 0, stream>>>(XPb, 256, nullptr, 0, W2c, nullptr, nullptr, X0b, nullptr, nullptr, Nn, 128);
    alpha_b<<<(Nn * 4 + 255) / 256, blk, 0, stream>>>(X0b, as2, ad2, AS, AD, Nn, 4, 32);
    launch_gather(ioff, csr, X0b, AS, AD, b2, Gb, Nn, 4, 32, 1, stream);
    gemm_rz<<<grz_128, blk, 0, stream>>>(Gb, 128, HINb, 128, Wr2c, Wz2c, br2, bz2, HINf, RHb, Zf, Nn, 128);
    gemm_t<8,3><<<g128_128, blk, 0, stream>>>(Gb, 128, RHb, 128, Wh2c, bh2, nullptr, X0b, HINf, Zf, Nn, 128);
    // X0b holds x2 (bf16)

    // ================= layer 3 (D=64, H=1, C=64) =================
    unsigned short* H3b  = HINb;                 // [N,64]
    unsigned short* XP3b = HINb + (size_t)Nn * 64;
    gemm_t<4,0><<<g64_64, blk, 0, stream>>>(X0b, 128, nullptr, 0, Wp3c, bp3, HINf, H3b, nullptr, nullptr, Nn, 64);
    gemm_t<4,0><<<g64_64, blk, 0, stream>>>(X0b, 128, nullptr, 0, W3c, nullptr, nullptr, XP3b, nullptr, nullptr, Nn, 64);
    alpha_b<<<(Nn + 255) / 256, blk, 0, stream>>>(XP3b, as3, ad3, AS, AD, Nn, 1, 64);
    launch_gather(ioff, csr, XP3b, AS, AD, b3, Gb, Nn, 1, 64, 0, stream);
    gemm_rz<<<grz_64, blk, 0, stream>>>(Gb, 64, H3b, 64, Wr3c, Wz3c, br3, bz3, HINf, RHb, Zf, Nn, 64);
    gemm_t<4,3><<<g64_64, blk, 0, stream>>>(Gb, 64, RHb, 64, Wh3c, bh3, (float*)d_out, nullptr, HINf, Zf, Nn, 64);
}

// Round 9
// 732.269 us; speedup vs baseline: 1.3700x; 1.1370x over previous
//
#include <hip/hip_runtime.h>

#define NEG_SLOPE 0.2f

typedef __attribute__((ext_vector_type(8))) short short8;
typedef __attribute__((ext_vector_type(8))) unsigned short ushort8;
typedef __attribute__((ext_vector_type(4))) float f32x4;

__device__ __forceinline__ unsigned short f2bf(float f) {
    unsigned int u = __float_as_uint(f);
    u += 0x7fff + ((u >> 16) & 1);     // round-to-nearest-even
    return (unsigned short)(u >> 16);
}
__device__ __forceinline__ float bf2f(unsigned short s) {
    return __uint_as_float(((unsigned int)s) << 16);
}

// async global->LDS, 16B per lane; lds base must be wave-uniform
__device__ __forceinline__ void gll16(const void* g, void* l) {
    __builtin_amdgcn_global_load_lds(
        (const __attribute__((address_space(1))) void*)g,
        (__attribute__((address_space(3))) void*)l, 16, 0, 0);
}

// ---------------- converters ----------------
__global__ void conv_k(const float* __restrict__ in, unsigned short* __restrict__ out, long n)
{
    long i = ((long)blockIdx.x * blockDim.x + threadIdx.x) * 4;
    if (i >= n) return;
    float4 f = *(const float4*)&in[i];
    ushort4 o; o.x = f2bf(f.x); o.y = f2bf(f.y); o.z = f2bf(f.z); o.w = f2bf(f.w);
    *(ushort4*)&out[i] = o;
}

// all 15 weights in one launch; supports column-offset packing into wider dst:
// Wc[((k>>3)*MoD + off + m)*8 + (k&7)] = bf16(W[k*MoS + m])
struct WPack {
    const float* W[15];
    unsigned short* Wc[15];
    int K[15];
    int MoS[15];
    int MoD[15];
    int off[15];
};
__global__ void convW_all(WPack p)
{
    int wi = blockIdx.y;
    int i = blockIdx.x * blockDim.x + threadIdx.x;
    int K = p.K[wi], MoS = p.MoS[wi];
    if (i >= K * MoS) return;
    int k = i / MoS, m = i % MoS;
    p.Wc[wi][((long)(k >> 3) * p.MoD[wi] + p.off[wi] + m) * 8 + (k & 7)] = f2bf(p.W[wi][i]);
}

// XCD-grouping remap (bijective with pad): consecutive work items share an XCD L2.
__device__ __forceinline__ int xcd_work(int TOT) {
    int L = blockIdx.x;
    int per = (TOT + 7) >> 3;
    int wk = (L & 7) * per + (L >> 3);
    return (wk < TOT) ? wk : -1;
}

// ================= bf16 MFMA GEMM: BM=64, BK=64, 4 waves (2x2) =================
// BN=128: wave tile 32x64 (2x4 frags). BN=64: wave tile 32x32 (2x2 frags).
// mode 0: outF/outB = acc+bias (either may be null)
// mode 3: o = (1-Zf)*HinF + Zf*tanh(acc+bias); outF/outB (GRU finish)
// mode 4: split projection: col<Mo/2 -> outF/outB = acc+bias[col] ([rows,Mo/2])
//         col>=Mo/2 -> outB2 = bf16(acc)                 ([rows,Mo/2])
template<int BN, int MODE>
__global__ __launch_bounds__(256) void gemm_t(
    const unsigned short* __restrict__ U, int K1,
    const unsigned short* __restrict__ V, int K2,
    const unsigned short* __restrict__ Wc, const float* __restrict__ bias,
    float* __restrict__ outF, unsigned short* __restrict__ outB,
    unsigned short* __restrict__ outB2,
    const float* __restrict__ HinF, const float* __restrict__ Zf,
    int rows, int Mo)
{
    constexpr int NIF = BN / 32;       // frags per wave in N (WC=2)
    __shared__ __align__(16) unsigned short As[8][64][8];    // 8KB
    __shared__ __align__(16) unsigned short Bs[8][BN][8];    // 16KB / 8KB
    const int CB = Mo / BN;
    const int RB = (rows + 63) >> 6;
    int wk = xcd_work(CB * RB);
    if (wk < 0) return;
    const int col0 = (wk % CB) * BN;
    const int row0 = (wk / CB) * 64;
    const int K = K1 + K2;
    const int tid = threadIdx.x;
    const int l = tid & 63, w = tid >> 6;
    const int lm = l & 15, lg = l >> 4;
    const int wrow = (w >> 1) * 32;
    const int wcol = (w & 1) * (BN / 2);
    f32x4 acc[2][NIF] = {};

    for (int k0 = 0; k0 < K; k0 += 64) {
#pragma unroll
        for (int i = 0; i < 2; ++i) {
            int c = i * 256 + tid;
            int m = c & 63, g = c >> 6;           // g wave-uniform
            int row = row0 + m; if (row >= rows) row = rows - 1;
            int k = k0 + g * 8;
            const unsigned short* sp = (k < K1) ? U + (long)row * K1 + k
                                                : V + (long)row * K2 + (k - K1);
            gll16(sp, &As[0][0][0] + ((i * 256 + w * 64) << 3));
        }
#pragma unroll
        for (int j = 0; j < NIF; ++j) {
            int c = j * 256 + tid;
            int n = c & (BN - 1), g = c / BN;     // g wave-uniform
            gll16(Wc + ((long)((k0 >> 3) + g) * Mo + (col0 + n)) * 8,
                  &Bs[0][0][0] + ((j * 256 + w * 64) << 3));
        }
        __syncthreads();
#pragma unroll
        for (int kk = 0; kk < 2; ++kk) {
            short8 a[2], b[NIF];
#pragma unroll
            for (int mi = 0; mi < 2; ++mi)
                a[mi] = *(const short8*)&As[kk * 4 + lg][wrow + mi * 16 + lm][0];
#pragma unroll
            for (int ni = 0; ni < NIF; ++ni)
                b[ni] = *(const short8*)&Bs[kk * 4 + lg][wcol + ni * 16 + lm][0];
#pragma unroll
            for (int mi = 0; mi < 2; ++mi)
#pragma unroll
                for (int ni = 0; ni < NIF; ++ni)
                    acc[mi][ni] = __builtin_amdgcn_mfma_f32_16x16x32_bf16(a[mi], b[ni], acc[mi][ni], 0, 0, 0);
        }
        __syncthreads();
    }

    const int halfMo = Mo >> 1;
#pragma unroll
    for (int mi = 0; mi < 2; ++mi) {
        int rbase = row0 + wrow + mi * 16 + lg * 4;
#pragma unroll
        for (int r = 0; r < 4; ++r) {
            int row = rbase + r;
            if (row >= rows) continue;
#pragma unroll
            for (int ni = 0; ni < NIF; ++ni) {
                int col = col0 + wcol + ni * 16 + lm;
                float v = acc[mi][ni][r];
                if (MODE == 0) {
                    v += (bias ? bias[col] : 0.f);
                    long idx = (long)row * Mo + col;
                    if (outF) outF[idx] = v;
                    if (outB) outB[idx] = f2bf(v);
                } else if (MODE == 3) {
                    v += bias[col];
                    long idx = (long)row * Mo + col;
                    float z  = Zf[idx];
                    float hh = tanhf(v);
                    float o  = (1.f - z) * HinF[idx] + z * hh;
                    if (outF) outF[idx] = o;
                    if (outB) outB[idx] = f2bf(o);
                } else {  // MODE 4
                    if (col < halfMo) {
                        v += bias[col];
                        long idx = (long)row * halfMo + col;
                        if (outF) outF[idx] = v;
                        outB[idx] = f2bf(v);
                    } else {
                        outB2[(long)row * halfMo + (col - halfMo)] = f2bf(v);
                    }
                }
            }
        }
    }
}

// ================= fused r+z dual-B GEMM: BM=64, BN=64, shared A =================
//   RHb = bf16( sigmoid(acc_r + br) * HinF ),  Zf = sigmoid(acc_z + bz)
__global__ __launch_bounds__(256) void gemm_rz(
    const unsigned short* __restrict__ U, int K1,
    const unsigned short* __restrict__ V, int K2,
    const unsigned short* __restrict__ Wrc, const unsigned short* __restrict__ Wzc,
    const float* __restrict__ br, const float* __restrict__ bz,
    const float* __restrict__ HinF,
    unsigned short* __restrict__ RHb, float* __restrict__ Zf,
    int rows, int Mo)
{
    __shared__ __align__(16) unsigned short As[8][64][8];   // 8KB
    __shared__ __align__(16) unsigned short Br[8][64][8];   // 8KB
    __shared__ __align__(16) unsigned short Bz[8][64][8];   // 8KB
    const int CB = Mo >> 6;
    const int RB = (rows + 63) >> 6;
    int wk = xcd_work(CB * RB);
    if (wk < 0) return;
    const int col0 = (wk % CB) * 64;
    const int row0 = (wk / CB) * 64;
    const int K = K1 + K2;
    const int tid = threadIdx.x;
    const int l = tid & 63, w = tid >> 6;
    const int lm = l & 15, lg = l >> 4;
    const int wrow = (w >> 1) * 32;
    const int wcol = (w & 1) * 32;
    f32x4 accr[2][2] = {}, accz[2][2] = {};

    for (int k0 = 0; k0 < K; k0 += 64) {
#pragma unroll
        for (int i = 0; i < 2; ++i) {
            int c = i * 256 + tid;
            int m = c & 63, g = c >> 6;
            int row = row0 + m; if (row >= rows) row = rows - 1;
            int k = k0 + g * 8;
            const unsigned short* sp = (k < K1) ? U + (long)row * K1 + k
                                                : V + (long)row * K2 + (k - K1);
            gll16(sp, &As[0][0][0] + ((i * 256 + w * 64) << 3));
        }
#pragma unroll
        for (int j = 0; j < 2; ++j) {
            int c = j * 256 + tid;
            int n = c & 63, g = c >> 6;
            long base = ((long)((k0 >> 3) + g) * Mo + (col0 + n)) * 8;
            gll16(Wrc + base, &Br[0][0][0] + ((j * 256 + w * 64) << 3));
            gll16(Wzc + base, &Bz[0][0][0] + ((j * 256 + w * 64) << 3));
        }
        __syncthreads();
#pragma unroll
        for (int kk = 0; kk < 2; ++kk) {
            short8 a[2], brv[2], bzv[2];
#pragma unroll
            for (int mi = 0; mi < 2; ++mi)
                a[mi] = *(const short8*)&As[kk * 4 + lg][wrow + mi * 16 + lm][0];
#pragma unroll
            for (int ni = 0; ni < 2; ++ni) {
                brv[ni] = *(const short8*)&Br[kk * 4 + lg][wcol + ni * 16 + lm][0];
                bzv[ni] = *(const short8*)&Bz[kk * 4 + lg][wcol + ni * 16 + lm][0];
            }
#pragma unroll
            for (int mi = 0; mi < 2; ++mi)
#pragma unroll
                for (int ni = 0; ni < 2; ++ni) {
                    accr[mi][ni] = __builtin_amdgcn_mfma_f32_16x16x32_bf16(a[mi], brv[ni], accr[mi][ni], 0, 0, 0);
                    accz[mi][ni] = __builtin_amdgcn_mfma_f32_16x16x32_bf16(a[mi], bzv[ni], accz[mi][ni], 0, 0, 0);
                }
        }
        __syncthreads();
    }

#pragma unroll
    for (int mi = 0; mi < 2; ++mi) {
        int rbase = row0 + wrow + mi * 16 + lg * 4;
#pragma unroll
        for (int r = 0; r < 4; ++r) {
            int row = rbase + r;
            if (row >= rows) continue;
#pragma unroll
            for (int ni = 0; ni < 2; ++ni) {
                int col = col0 + wcol + ni * 16 + lm;
                long idx = (long)row * Mo + col;
                float rv = 1.f / (1.f + __expf(-(accr[mi][ni][r] + br[col])));
                float zv = 1.f / (1.f + __expf(-(accz[mi][ni][r] + bz[col])));
                RHb[idx] = f2bf(rv * HinF[idx]);
                Zf[idx] = zv;
            }
        }
    }
}

// ---------------- alpha (bf16 input) ----------------
__global__ void alpha_b(const unsigned short* __restrict__ XPb,
                        const float* __restrict__ a_s, const float* __restrict__ a_d,
                        float* __restrict__ AS, float* __restrict__ AD,
                        int Nn, int H, int C)
{
    int i = blockIdx.x * blockDim.x + threadIdx.x;
    if (i >= Nn * H) return;
    int n = i / H, h = i % H;
    const unsigned short* xp = &XPb[(long)n * H * C + (long)h * C];
    float ss = 0.f, sd = 0.f;
    for (int c = 0; c < C; ++c) {
        float v = bf2f(xp[c]);
        ss += v * a_s[h * C + c];
        sd += v * a_d[h * C + c];
    }
    AS[i] = ss; AD[i] = sd;
}

// ---------------- CSR build ----------------
__global__ void count_k(const int* __restrict__ dst, int E, int* __restrict__ cnt)
{
    int e = blockIdx.x * blockDim.x + threadIdx.x;
    if (e < E) atomicAdd(&cnt[dst[e]], 1);
}

__global__ __launch_bounds__(1024) void scan_k(const int* __restrict__ cnt, int Nn,
                                               int* __restrict__ off)
{
    __shared__ int part[1024];
    int tid = threadIdx.x;
    int chunk = (Nn + 1023) / 1024;
    int b = tid * chunk;
    int e = b + chunk; if (e > Nn) e = Nn; if (b > Nn) b = Nn;
    int s = 0;
    for (int i = b; i < e; ++i) s += cnt[i];
    part[tid] = s;
    __syncthreads();
    for (int d = 1; d < 1024; d <<= 1) {
        int v = (tid >= d) ? part[tid - d] : 0;
        __syncthreads();
        part[tid] += v;
        __syncthreads();
    }
    int run = tid ? part[tid - 1] : 0;
    for (int i = b; i < e; ++i) { off[i] = run; run += cnt[i]; }
    if (tid == 1023) off[Nn] = part[1023];
}

__global__ void scatter_k(const int* __restrict__ src, const int* __restrict__ dst, int E,
                          const int* __restrict__ off, int* __restrict__ cur,
                          int* __restrict__ csr_src)
{
    int e = blockIdx.x * blockDim.x + threadIdx.x;
    if (e < E) {
        int d = dst[e];
        int p = atomicAdd(&cur[d], 1);
        csr_src[off[d] + p] = src[e];
    }
}

// ---------------- bf16 GAT gather (8 feats/lane) ----------------
__global__ void gat_gather_b(const int* __restrict__ off, const int* __restrict__ csr_src,
                             const unsigned short* __restrict__ XPb,
                             const float* __restrict__ AS, const float* __restrict__ AD,
                             const float* __restrict__ bias,
                             unsigned short* __restrict__ Gout,
                             int Nn, int H, int C, int do_elu)
{
    const int D = H * C;
    const int lpn = D >> 3;
    const int npw = 64 / lpn;
    int lane = threadIdx.x & 63;
    long wave = ((long)blockIdx.x * blockDim.x + threadIdx.x) >> 6;
    int sub = lane / lpn;
    int cl = lane % lpn;
    long n = wave * npw + sub;
    if (n >= Nn) return;
    int j = cl * 8;
    int h = j / C;
    float ad = AD[n * H + h];
    float v = AS[n * H + h] + ad;
    v = v > 0.f ? v : NEG_SLOPE * v;
    float w = __expf(v);
    float den = w;
    float acc[8];
    {
        ushort8 xv = *(const ushort8*)&XPb[(long)n * D + j];
#pragma unroll
        for (int q = 0; q < 8; ++q) acc[q] = w * bf2f(xv[q]);
    }
    int b0 = off[n], b1 = off[n + 1];
    for (int i = b0; i < b1; ++i) {
        int s = csr_src[i];
        v = AS[s * H + h] + ad;
        v = v > 0.f ? v : NEG_SLOPE * v;
        w = __expf(v);
        den += w;
        ushort8 xv = *(const ushort8*)&XPb[(long)s * D + j];
#pragma unroll
        for (int q = 0; q < 8; ++q) acc[q] += w * bf2f(xv[q]);
    }
    float inv = 1.f / (den + 1e-16f);
    ushort8 ov;
#pragma unroll
    for (int q = 0; q < 8; ++q) {
        float o = acc[q] * inv + bias[j + q];
        if (do_elu) o = o > 0.f ? o : expm1f(o);
        ov[q] = f2bf(o);
    }
    *(ushort8*)&Gout[(long)n * D + j] = ov;
}

static inline int pad8(int t) { return ((t + 7) / 8) * 8; }
static inline int gblocks(int rows, int Mo, int BN) {
    return pad8((Mo / BN) * ((rows + 63) >> 6));
}

static inline void launch_gather(const int* ioff, const int* csr,
                                 const unsigned short* xp, const float* AS, const float* AD,
                                 const float* bias, unsigned short* gout,
                                 int Nn, int H, int C, int elu, hipStream_t stream)
{
    int D = H * C;
    int lpn = D >> 3;
    int npw = 64 / lpn;
    long waves = (Nn + npw - 1) / npw;
    int blocks = (int)((waves * 64 + 255) / 256);
    gat_gather_b<<<blocks, 256, 0, stream>>>(ioff, csr, xp, AS, AD, bias, gout, Nn, H, C, elu);
}

extern "C" void kernel_launch(void* const* d_in, const int* in_sizes, int n_in,
                              void* d_out, int out_size, void* d_ws, size_t ws_size,
                              hipStream_t stream)
{
    const float* x    = (const float*)d_in[0];
    const int*   ei   = (const int*)  d_in[1];
    const float* W_tr = (const float*)d_in[2];
    const float* b_tr = (const float*)d_in[3];
    const float* W1   = (const float*)d_in[4];
    const float* as1  = (const float*)d_in[5];
    const float* ad1  = (const float*)d_in[6];
    const float* b1   = (const float*)d_in[7];
    const float* Wr1  = (const float*)d_in[8];
    const float* br1  = (const float*)d_in[9];
    const float* Wz1  = (const float*)d_in[10];
    const float* bz1  = (const float*)d_in[11];
    const float* Wh1  = (const float*)d_in[12];
    const float* bh1  = (const float*)d_in[13];
    const float* Wp2  = (const float*)d_in[14];
    const float* bp2  = (const float*)d_in[15];
    const float* W2   = (const float*)d_in[16];
    const float* as2  = (const float*)d_in[17];
    const float* ad2  = (const float*)d_in[18];
    const float* b2   = (const float*)d_in[19];
    const float* Wr2  = (const float*)d_in[20];
    const float* br2  = (const float*)d_in[21];
    const float* Wz2  = (const float*)d_in[22];
    const float* bz2  = (const float*)d_in[23];
    const float* Wh2  = (const float*)d_in[24];
    const float* bh2  = (const float*)d_in[25];
    const float* Wp3  = (const float*)d_in[26];
    const float* bp3  = (const float*)d_in[27];
    const float* W3   = (const float*)d_in[28];
    const float* as3  = (const float*)d_in[29];
    const float* ad3  = (const float*)d_in[30];
    const float* b3   = (const float*)d_in[31];
    const float* Wr3  = (const float*)d_in[32];
    const float* br3  = (const float*)d_in[33];
    const float* Wz3  = (const float*)d_in[34];
    const float* bz3  = (const float*)d_in[35];
    const float* Wh3  = (const float*)d_in[36];
    const float* bh3  = (const float*)d_in[37];

    const int Nn = in_sizes[0] / 128;   // 50000
    const int E  = in_sizes[1] / 2;     // 800000
    const int* srcp = ei;
    const int* dstp = ei + E;

    // ---------------- workspace layout ----------------
    float* X0f  = (float*)d_ws;                         // [N,256] fp32 (L1 hin)
    float* HINf = X0f  + (size_t)Nn * 256;              // [N,128] fp32 (L2 hin; L3 [N,64])
    float* Zf   = HINf + (size_t)Nn * 128;              // [N,256] fp32 (z-gate)
    float* AS   = Zf   + (size_t)Nn * 256;              // [N,8]
    float* AD   = AS   + (size_t)Nn * 8;                // [N,8]
    unsigned short* X0b  = (unsigned short*)(AD + (size_t)Nn * 8); // [N,256]
    unsigned short* XPb  = X0b + (size_t)Nn * 256;      // [N,256]
    unsigned short* Gb   = XPb + (size_t)Nn * 256;      // [N,256]
    unsigned short* RHb  = Gb  + (size_t)Nn * 256;      // [N,256]
    unsigned short* HINb = RHb + (size_t)Nn * 256;      // [N,128]
    unsigned short* wpool = HINb + (size_t)Nn * 128;
    unsigned short* Wtrc   = wpool;                     // 128*256
    unsigned short* W1c    = Wtrc   + 128 * 256;        // 256*256
    unsigned short* Wr1c   = W1c    + 256 * 256;        // 512*256
    unsigned short* Wz1c   = Wr1c   + 512 * 256;
    unsigned short* Wh1c   = Wz1c   + 512 * 256;
    unsigned short* Wp2W2c = Wh1c   + 512 * 256;        // 256*256 combined
    unsigned short* Wr2c   = Wp2W2c + 256 * 256;        // 256*128
    unsigned short* Wz2c   = Wr2c   + 256 * 128;
    unsigned short* Wh2c   = Wz2c   + 256 * 128;
    unsigned short* Wp3W3c = Wh2c   + 256 * 128;        // 128*128 combined
    unsigned short* Wr3c   = Wp3W3c + 128 * 128;        // 128*64
    unsigned short* Wz3c   = Wr3c   + 128 * 64;
    unsigned short* Wh3c   = Wz3c   + 128 * 64;
    int* ioff = (int*)(((size_t)(Wh3c + 128 * 64) + 15) & ~(size_t)15);
    int* cnt  = ioff + (Nn + 1);
    int* cur  = cnt + Nn;
    int* csr  = cur + Nn;

    dim3 blk(256);

    // ---------- all 15 weight conversions in ONE launch ----------
    {
        WPack p;
        const float* Ws[15]     = {W_tr, W1, Wr1, Wz1, Wh1,
                                   Wp2, W2, Wr2, Wz2, Wh2,
                                   Wp3, W3, Wr3, Wz3, Wh3};
        unsigned short* Wcs[15] = {Wtrc, W1c, Wr1c, Wz1c, Wh1c,
                                   Wp2W2c, Wp2W2c, Wr2c, Wz2c, Wh2c,
                                   Wp3W3c, Wp3W3c, Wr3c, Wz3c, Wh3c};
        int Ks[15]   = {128, 256, 512, 512, 512, 256, 256, 256, 256, 256, 128, 128, 128, 128, 128};
        int MoSs[15] = {256, 256, 256, 256, 256, 128, 128, 128, 128, 128, 64, 64, 64, 64, 64};
        int MoDs[15] = {256, 256, 256, 256, 256, 256, 256, 128, 128, 128, 128, 128, 64, 64, 64};
        int offs[15] = {0, 0, 0, 0, 0, 0, 128, 0, 0, 0, 0, 64, 0, 0, 0};
        for (int i = 0; i < 15; ++i) {
            p.W[i] = Ws[i]; p.Wc[i] = Wcs[i]; p.K[i] = Ks[i];
            p.MoS[i] = MoSs[i]; p.MoD[i] = MoDs[i]; p.off[i] = offs[i];
        }
        convW_all<<<dim3((512 * 256 + 255) / 256, 15), blk, 0, stream>>>(p);
    }

    // ---------- CSR build ----------
    hipMemsetAsync(cnt, 0, (size_t)Nn * 4, stream);
    hipMemsetAsync(cur, 0, (size_t)Nn * 4, stream);
    count_k<<<(E + 255) / 256, blk, 0, stream>>>(dstp, E, cnt);
    scan_k<<<1, 1024, 0, stream>>>(cnt, Nn, ioff);
    scatter_k<<<(E + 255) / 256, blk, 0, stream>>>(srcp, dstp, E, ioff, cur, csr);

    // ---------- stage 0: X0 = x @ W_tr + b_tr (dual write) ----------
    unsigned short* xb = Gb;   // Gb free until gather1
    conv_k<<<(int)(((long)Nn * 128 / 4 + 255) / 256), blk, 0, stream>>>(x, xb, (long)Nn * 128);
    gemm_t<128,0><<<gblocks(Nn, 256, 128), blk, 0, stream>>>(
        xb, 128, nullptr, 0, Wtrc, b_tr, X0f, X0b, nullptr, nullptr, nullptr, Nn, 256);

    // ================= layer 1 (D=256, H=8, C=32) =================
    gemm_t<128,0><<<gblocks(Nn, 256, 128), blk, 0, stream>>>(
        X0b, 256, nullptr, 0, W1c, nullptr, nullptr, XPb, nullptr, nullptr, nullptr, Nn, 256);
    alpha_b<<<(Nn * 8 + 255) / 256, blk, 0, stream>>>(XPb, as1, ad1, AS, AD, Nn, 8, 32);
    launch_gather(ioff, csr, XPb, AS, AD, b1, Gb, Nn, 8, 32, 1, stream);
    gemm_rz<<<gblocks(Nn, 256, 64), blk, 0, stream>>>(
        Gb, 256, X0b, 256, Wr1c, Wz1c, br1, bz1, X0f, RHb, Zf, Nn, 256);
    gemm_t<128,3><<<gblocks(Nn, 256, 128), blk, 0, stream>>>(
        Gb, 256, RHb, 256, Wh1c, bh1, nullptr, XPb, nullptr, X0f, Zf, Nn, 256);
    // XPb holds x1 (bf16)

    // ================= layer 2 (D=128, H=4, C=32) =================
    gemm_t<128,4><<<gblocks(Nn, 256, 128), blk, 0, stream>>>(
        XPb, 256, nullptr, 0, Wp2W2c, bp2, HINf, HINb, X0b, nullptr, nullptr, Nn, 256);
    alpha_b<<<(Nn * 4 + 255) / 256, blk, 0, stream>>>(X0b, as2, ad2, AS, AD, Nn, 4, 32);
    launch_gather(ioff, csr, X0b, AS, AD, b2, Gb, Nn, 4, 32, 1, stream);
    gemm_rz<<<gblocks(Nn, 128, 64), blk, 0, stream>>>(
        Gb, 128, HINb, 128, Wr2c, Wz2c, br2, bz2, HINf, RHb, Zf, Nn, 128);
    gemm_t<128,3><<<gblocks(Nn, 128, 128), blk, 0, stream>>>(
        Gb, 128, RHb, 128, Wh2c, bh2, nullptr, X0b, nullptr, HINf, Zf, Nn, 128);
    // X0b holds x2 (bf16)

    // ================= layer 3 (D=64, H=1, C=64) =================
    unsigned short* H3b  = HINb;                 // [N,64]
    unsigned short* XP3b = HINb + (size_t)Nn * 64;
    gemm_t<128,4><<<gblocks(Nn, 128, 128), blk, 0, stream>>>(
        X0b, 128, nullptr, 0, Wp3W3c, bp3, HINf, H3b, XP3b, nullptr, nullptr, Nn, 128);
    alpha_b<<<(Nn + 255) / 256, blk, 0, stream>>>(XP3b, as3, ad3, AS, AD, Nn, 1, 64);
    launch_gather(ioff, csr, XP3b, AS, AD, b3, Gb, Nn, 1, 64, 0, stream);
    gemm_rz<<<gblocks(Nn, 64, 64), blk, 0, stream>>>(
        Gb, 64, H3b, 64, Wr3c, Wz3c, br3, bz3, HINf, RHb, Zf, Nn, 64);
    gemm_t<64,3><<<gblocks(Nn, 64, 64), blk, 0, stream>>>(
        Gb, 64, RHb, 64, Wh3c, bh3, (float*)d_out, nullptr, nullptr, HINf, Zf, Nn, 64);
}

// Round 10
// 656.200 us; speedup vs baseline: 1.5288x; 1.1159x over previous
//
#include <hip/hip_runtime.h>

#define NEG_SLOPE 0.2f

typedef __attribute__((ext_vector_type(8))) short short8;
typedef __attribute__((ext_vector_type(8))) unsigned short ushort8;
typedef __attribute__((ext_vector_type(4))) float f32x4;

__device__ __forceinline__ unsigned short f2bf(float f) {
    unsigned int u = __float_as_uint(f);
    u += 0x7fff + ((u >> 16) & 1);     // round-to-nearest-even
    return (unsigned short)(u >> 16);
}
__device__ __forceinline__ float bf2f(unsigned short s) {
    return __uint_as_float(((unsigned int)s) << 16);
}

// async global->LDS, 16B per lane; lds base must be wave-uniform
__device__ __forceinline__ void gll16(const void* g, void* l) {
    __builtin_amdgcn_global_load_lds(
        (const __attribute__((address_space(1))) void*)g,
        (__attribute__((address_space(3))) void*)l, 16, 0, 0);
}

// ---------------- converters ----------------
__global__ void conv_k(const float* __restrict__ in, unsigned short* __restrict__ out, long n)
{
    long i = ((long)blockIdx.x * blockDim.x + threadIdx.x) * 4;
    if (i >= n) return;
    float4 f = *(const float4*)&in[i];
    ushort4 o; o.x = f2bf(f.x); o.y = f2bf(f.y); o.z = f2bf(f.z); o.w = f2bf(f.w);
    *(ushort4*)&out[i] = o;
}

// all 15 weights in one launch; supports column-offset packing into wider dst:
// Wc[((k>>3)*MoD + off + m)*8 + (k&7)] = bf16(W[k*MoS + m])
struct WPack {
    const float* W[15];
    unsigned short* Wc[15];
    int K[15];
    int MoS[15];
    int MoD[15];
    int off[15];
};
__global__ void convW_all(WPack p)
{
    int wi = blockIdx.y;
    int i = blockIdx.x * blockDim.x + threadIdx.x;
    int K = p.K[wi], MoS = p.MoS[wi];
    if (i >= K * MoS) return;
    int k = i / MoS, m = i % MoS;
    p.Wc[wi][((long)(k >> 3) * p.MoD[wi] + p.off[wi] + m) * 8 + (k & 7)] = f2bf(p.W[wi][i]);
}

// XCD-grouping remap (bijective with pad): consecutive work items share an XCD L2.
__device__ __forceinline__ int xcd_work(int TOT) {
    int L = blockIdx.x;
    int per = (TOT + 7) >> 3;
    int wk = (L & 7) * per + (L >> 3);
    return (wk < TOT) ? wk : -1;
}

// ================= bf16 MFMA GEMM: BM=64, BK=64, 4 waves (2x2) =================
// BN=128: wave tile 32x64 (2x4 frags). BN=64: wave tile 32x32 (2x2 frags).
// MODE 0: outF/outB = acc+bias (either may be null)
// MODE 3: o = (1-z)*hin + z*tanh(acc+bias), z/hin bf16; outB   (GRU finish, L1/L2)
// MODE 4: split projection: col<Mo/2 -> outF/outB = acc+bias[col] ([rows,Mo/2])
//         col>=Mo/2 -> outB2 = bf16(acc)                         ([rows,Mo/2])
// MODE 5: o = (1-Zf)*HinF + Zf*tanh(acc+bias); outF fp32        (GRU finish, L3)
template<int BN, int MODE>
__global__ __launch_bounds__(256) void gemm_t(
    const unsigned short* __restrict__ U, int K1,
    const unsigned short* __restrict__ V, int K2,
    const unsigned short* __restrict__ Wc, const float* __restrict__ bias,
    float* __restrict__ outF, unsigned short* __restrict__ outB,
    unsigned short* __restrict__ outB2,
    const unsigned short* __restrict__ HinB, const unsigned short* __restrict__ Zb,
    const float* __restrict__ HinF, const float* __restrict__ Zf,
    int rows, int Mo)
{
    constexpr int NIF = BN / 32;       // frags per wave in N (WC=2)
    __shared__ __align__(16) unsigned short As[8][64][8];    // 8KB
    __shared__ __align__(16) unsigned short Bs[8][BN][8];    // 16KB / 8KB
    const int CB = Mo / BN;
    const int RB = (rows + 63) >> 6;
    int wk = xcd_work(CB * RB);
    if (wk < 0) return;
    const int col0 = (wk % CB) * BN;
    const int row0 = (wk / CB) * 64;
    const int K = K1 + K2;
    const int tid = threadIdx.x;
    const int l = tid & 63, w = tid >> 6;
    const int lm = l & 15, lg = l >> 4;
    const int wrow = (w >> 1) * 32;
    const int wcol = (w & 1) * (BN / 2);
    f32x4 acc[2][NIF] = {};

    for (int k0 = 0; k0 < K; k0 += 64) {
#pragma unroll
        for (int i = 0; i < 2; ++i) {
            int c = i * 256 + tid;
            int m = c & 63, g = c >> 6;           // g wave-uniform
            int row = row0 + m; if (row >= rows) row = rows - 1;
            int k = k0 + g * 8;
            const unsigned short* sp = (k < K1) ? U + (long)row * K1 + k
                                                : V + (long)row * K2 + (k - K1);
            gll16(sp, &As[0][0][0] + ((i * 256 + w * 64) << 3));
        }
#pragma unroll
        for (int j = 0; j < NIF; ++j) {
            int c = j * 256 + tid;
            int n = c & (BN - 1), g = c / BN;     // g wave-uniform
            gll16(Wc + ((long)((k0 >> 3) + g) * Mo + (col0 + n)) * 8,
                  &Bs[0][0][0] + ((j * 256 + w * 64) << 3));
        }
        __syncthreads();
#pragma unroll
        for (int kk = 0; kk < 2; ++kk) {
            short8 a[2], b[NIF];
#pragma unroll
            for (int mi = 0; mi < 2; ++mi)
                a[mi] = *(const short8*)&As[kk * 4 + lg][wrow + mi * 16 + lm][0];
#pragma unroll
            for (int ni = 0; ni < NIF; ++ni)
                b[ni] = *(const short8*)&Bs[kk * 4 + lg][wcol + ni * 16 + lm][0];
#pragma unroll
            for (int mi = 0; mi < 2; ++mi)
#pragma unroll
                for (int ni = 0; ni < NIF; ++ni)
                    acc[mi][ni] = __builtin_amdgcn_mfma_f32_16x16x32_bf16(a[mi], b[ni], acc[mi][ni], 0, 0, 0);
        }
        __syncthreads();
    }

    const int halfMo = Mo >> 1;
#pragma unroll
    for (int mi = 0; mi < 2; ++mi) {
        int rbase = row0 + wrow + mi * 16 + lg * 4;
#pragma unroll
        for (int r = 0; r < 4; ++r) {
            int row = rbase + r;
            if (row >= rows) continue;
#pragma unroll
            for (int ni = 0; ni < NIF; ++ni) {
                int col = col0 + wcol + ni * 16 + lm;
                float v = acc[mi][ni][r];
                if (MODE == 0) {
                    v += (bias ? bias[col] : 0.f);
                    long idx = (long)row * Mo + col;
                    if (outF) outF[idx] = v;
                    if (outB) outB[idx] = f2bf(v);
                } else if (MODE == 3) {
                    v += bias[col];
                    long idx = (long)row * Mo + col;
                    float z = bf2f(Zb[idx]);
                    float o = (1.f - z) * bf2f(HinB[idx]) + z * tanhf(v);
                    outB[idx] = f2bf(o);
                } else if (MODE == 5) {
                    v += bias[col];
                    long idx = (long)row * Mo + col;
                    float z = Zf[idx];
                    float o = (1.f - z) * HinF[idx] + z * tanhf(v);
                    outF[idx] = o;
                } else {  // MODE 4
                    if (col < halfMo) {
                        v += bias[col];
                        long idx = (long)row * halfMo + col;
                        if (outF) outF[idx] = v;
                        outB[idx] = f2bf(v);
                    } else {
                        outB2[(long)row * halfMo + (col - halfMo)] = f2bf(v);
                    }
                }
            }
        }
    }
}

// ================= fused r+z dual-B GEMM: BM=64, BN=64, shared A =================
// FP=0: hin/z in bf16 (L1/L2);  FP=1: hin/z in fp32 (L3)
//   RHb = bf16( sigmoid(acc_r + br) * hin ),  Zout = sigmoid(acc_z + bz)
template<int FP>
__global__ __launch_bounds__(256) void gemm_rz(
    const unsigned short* __restrict__ U, int K1,
    const unsigned short* __restrict__ V, int K2,
    const unsigned short* __restrict__ Wrc, const unsigned short* __restrict__ Wzc,
    const float* __restrict__ br, const float* __restrict__ bz,
    const unsigned short* __restrict__ HinB, const float* __restrict__ HinF,
    unsigned short* __restrict__ RHb,
    unsigned short* __restrict__ ZoutB, float* __restrict__ ZoutF,
    int rows, int Mo)
{
    __shared__ __align__(16) unsigned short As[8][64][8];   // 8KB
    __shared__ __align__(16) unsigned short Br[8][64][8];   // 8KB
    __shared__ __align__(16) unsigned short Bz[8][64][8];   // 8KB
    const int CB = Mo >> 6;
    const int RB = (rows + 63) >> 6;
    int wk = xcd_work(CB * RB);
    if (wk < 0) return;
    const int col0 = (wk % CB) * 64;
    const int row0 = (wk / CB) * 64;
    const int K = K1 + K2;
    const int tid = threadIdx.x;
    const int l = tid & 63, w = tid >> 6;
    const int lm = l & 15, lg = l >> 4;
    const int wrow = (w >> 1) * 32;
    const int wcol = (w & 1) * 32;
    f32x4 accr[2][2] = {}, accz[2][2] = {};

    for (int k0 = 0; k0 < K; k0 += 64) {
#pragma unroll
        for (int i = 0; i < 2; ++i) {
            int c = i * 256 + tid;
            int m = c & 63, g = c >> 6;
            int row = row0 + m; if (row >= rows) row = rows - 1;
            int k = k0 + g * 8;
            const unsigned short* sp = (k < K1) ? U + (long)row * K1 + k
                                                : V + (long)row * K2 + (k - K1);
            gll16(sp, &As[0][0][0] + ((i * 256 + w * 64) << 3));
        }
#pragma unroll
        for (int j = 0; j < 2; ++j) {
            int c = j * 256 + tid;
            int n = c & 63, g = c >> 6;
            long base = ((long)((k0 >> 3) + g) * Mo + (col0 + n)) * 8;
            gll16(Wrc + base, &Br[0][0][0] + ((j * 256 + w * 64) << 3));
            gll16(Wzc + base, &Bz[0][0][0] + ((j * 256 + w * 64) << 3));
        }
        __syncthreads();
#pragma unroll
        for (int kk = 0; kk < 2; ++kk) {
            short8 a[2], brv[2], bzv[2];
#pragma unroll
            for (int mi = 0; mi < 2; ++mi)
                a[mi] = *(const short8*)&As[kk * 4 + lg][wrow + mi * 16 + lm][0];
#pragma unroll
            for (int ni = 0; ni < 2; ++ni) {
                brv[ni] = *(const short8*)&Br[kk * 4 + lg][wcol + ni * 16 + lm][0];
                bzv[ni] = *(const short8*)&Bz[kk * 4 + lg][wcol + ni * 16 + lm][0];
            }
#pragma unroll
            for (int mi = 0; mi < 2; ++mi)
#pragma unroll
                for (int ni = 0; ni < 2; ++ni) {
                    accr[mi][ni] = __builtin_amdgcn_mfma_f32_16x16x32_bf16(a[mi], brv[ni], accr[mi][ni], 0, 0, 0);
                    accz[mi][ni] = __builtin_amdgcn_mfma_f32_16x16x32_bf16(a[mi], bzv[ni], accz[mi][ni], 0, 0, 0);
                }
        }
        __syncthreads();
    }

#pragma unroll
    for (int mi = 0; mi < 2; ++mi) {
        int rbase = row0 + wrow + mi * 16 + lg * 4;
#pragma unroll
        for (int r = 0; r < 4; ++r) {
            int row = rbase + r;
            if (row >= rows) continue;
#pragma unroll
            for (int ni = 0; ni < 2; ++ni) {
                int col = col0 + wcol + ni * 16 + lm;
                long idx = (long)row * Mo + col;
                float rv = 1.f / (1.f + __expf(-(accr[mi][ni][r] + br[col])));
                float zv = 1.f / (1.f + __expf(-(accz[mi][ni][r] + bz[col])));
                float hin = FP ? HinF[idx] : bf2f(HinB[idx]);
                RHb[idx] = f2bf(rv * hin);
                if (FP) ZoutF[idx] = zv;
                else    ZoutB[idx] = f2bf(zv);
            }
        }
    }
}

// ---------------- alpha (bf16 input) ----------------
__global__ void alpha_b(const unsigned short* __restrict__ XPb,
                        const float* __restrict__ a_s, const float* __restrict__ a_d,
                        float* __restrict__ AS, float* __restrict__ AD,
                        int Nn, int H, int C)
{
    int i = blockIdx.x * blockDim.x + threadIdx.x;
    if (i >= Nn * H) return;
    int n = i / H, h = i % H;
    const unsigned short* xp = &XPb[(long)n * H * C + (long)h * C];
    float ss = 0.f, sd = 0.f;
    for (int c = 0; c < C; ++c) {
        float v = bf2f(xp[c]);
        ss += v * a_s[h * C + c];
        sd += v * a_d[h * C + c];
    }
    AS[i] = ss; AD[i] = sd;
}

// ---------------- CSR build ----------------
__global__ void count_k(const int* __restrict__ dst, int E, int* __restrict__ cnt)
{
    int e = blockIdx.x * blockDim.x + threadIdx.x;
    if (e < E) atomicAdd(&cnt[dst[e]], 1);
}

__global__ __launch_bounds__(1024) void scan_k(const int* __restrict__ cnt, int Nn,
                                               int* __restrict__ off)
{
    __shared__ int part[1024];
    int tid = threadIdx.x;
    int chunk = (Nn + 1023) / 1024;
    int b = tid * chunk;
    int e = b + chunk; if (e > Nn) e = Nn; if (b > Nn) b = Nn;
    int s = 0;
    for (int i = b; i < e; ++i) s += cnt[i];
    part[tid] = s;
    __syncthreads();
    for (int d = 1; d < 1024; d <<= 1) {
        int v = (tid >= d) ? part[tid - d] : 0;
        __syncthreads();
        part[tid] += v;
        __syncthreads();
    }
    int run = tid ? part[tid - 1] : 0;
    for (int i = b; i < e; ++i) { off[i] = run; run += cnt[i]; }
    if (tid == 1023) off[Nn] = part[1023];
}

__global__ void scatter_k(const int* __restrict__ src, const int* __restrict__ dst, int E,
                          const int* __restrict__ off, int* __restrict__ cur,
                          int* __restrict__ csr_src)
{
    int e = blockIdx.x * blockDim.x + threadIdx.x;
    if (e < E) {
        int d = dst[e];
        int p = atomicAdd(&cur[d], 1);
        csr_src[off[d] + p] = src[e];
    }
}

// ---------------- bf16 GAT gather (8 feats/lane, 4x-unrolled edge loop) ----------------
__global__ void gat_gather_b(const int* __restrict__ off, const int* __restrict__ csr_src,
                             const unsigned short* __restrict__ XPb,
                             const float* __restrict__ AS, const float* __restrict__ AD,
                             const float* __restrict__ bias,
                             unsigned short* __restrict__ Gout,
                             int Nn, int H, int C, int do_elu)
{
    const int D = H * C;
    const int lpn = D >> 3;
    const int npw = 64 / lpn;
    int lane = threadIdx.x & 63;
    long wave = ((long)blockIdx.x * blockDim.x + threadIdx.x) >> 6;
    int sub = lane / lpn;
    int cl = lane % lpn;
    long n = wave * npw + sub;
    if (n >= Nn) return;
    int j = cl * 8;
    int h = j / C;
    float ad = AD[n * H + h];
    float v = AS[n * H + h] + ad;
    v = v > 0.f ? v : NEG_SLOPE * v;
    float w = __expf(v);
    float den = w;
    float acc[8];
    {
        ushort8 xv = *(const ushort8*)&XPb[(long)n * D + j];
#pragma unroll
        for (int q = 0; q < 8; ++q) acc[q] = w * bf2f(xv[q]);
    }
    int b0 = off[n], b1 = off[n + 1];
    int i = b0;
    for (; i + 4 <= b1; i += 4) {
        int s0 = csr_src[i + 0];
        int s1 = csr_src[i + 1];
        int s2 = csr_src[i + 2];
        int s3 = csr_src[i + 3];
        float v0 = AS[s0 * H + h] + ad;
        float v1 = AS[s1 * H + h] + ad;
        float v2 = AS[s2 * H + h] + ad;
        float v3 = AS[s3 * H + h] + ad;
        v0 = v0 > 0.f ? v0 : NEG_SLOPE * v0;
        v1 = v1 > 0.f ? v1 : NEG_SLOPE * v1;
        v2 = v2 > 0.f ? v2 : NEG_SLOPE * v2;
        v3 = v3 > 0.f ? v3 : NEG_SLOPE * v3;
        float w0 = __expf(v0), w1 = __expf(v1), w2 = __expf(v2), w3 = __expf(v3);
        den += (w0 + w1) + (w2 + w3);
        ushort8 x0 = *(const ushort8*)&XPb[(long)s0 * D + j];
        ushort8 x1 = *(const ushort8*)&XPb[(long)s1 * D + j];
        ushort8 x2 = *(const ushort8*)&XPb[(long)s2 * D + j];
        ushort8 x3 = *(const ushort8*)&XPb[(long)s3 * D + j];
#pragma unroll
        for (int q = 0; q < 8; ++q)
            acc[q] += w0 * bf2f(x0[q]) + w1 * bf2f(x1[q]) + w2 * bf2f(x2[q]) + w3 * bf2f(x3[q]);
    }
    for (; i < b1; ++i) {
        int s = csr_src[i];
        v = AS[s * H + h] + ad;
        v = v > 0.f ? v : NEG_SLOPE * v;
        w = __expf(v);
        den += w;
        ushort8 xv = *(const ushort8*)&XPb[(long)s * D + j];
#pragma unroll
        for (int q = 0; q < 8; ++q) acc[q] += w * bf2f(xv[q]);
    }
    float inv = 1.f / (den + 1e-16f);
    ushort8 ov;
#pragma unroll
    for (int q = 0; q < 8; ++q) {
        float o = acc[q] * inv + bias[j + q];
        if (do_elu) o = o > 0.f ? o : expm1f(o);
        ov[q] = f2bf(o);
    }
    *(ushort8*)&Gout[(long)n * D + j] = ov;
}

static inline int pad8(int t) { return ((t + 7) / 8) * 8; }
static inline int gblocks(int rows, int Mo, int BN) {
    return pad8((Mo / BN) * ((rows + 63) >> 6));
}

static inline void launch_gather(const int* ioff, const int* csr,
                                 const unsigned short* xp, const float* AS, const float* AD,
                                 const float* bias, unsigned short* gout,
                                 int Nn, int H, int C, int elu, hipStream_t stream)
{
    int D = H * C;
    int lpn = D >> 3;
    int npw = 64 / lpn;
    long waves = (Nn + npw - 1) / npw;
    int blocks = (int)((waves * 64 + 255) / 256);
    gat_gather_b<<<blocks, 256, 0, stream>>>(ioff, csr, xp, AS, AD, bias, gout, Nn, H, C, elu);
}

extern "C" void kernel_launch(void* const* d_in, const int* in_sizes, int n_in,
                              void* d_out, int out_size, void* d_ws, size_t ws_size,
                              hipStream_t stream)
{
    const float* x    = (const float*)d_in[0];
    const int*   ei   = (const int*)  d_in[1];
    const float* W_tr = (const float*)d_in[2];
    const float* b_tr = (const float*)d_in[3];
    const float* W1   = (const float*)d_in[4];
    const float* as1  = (const float*)d_in[5];
    const float* ad1  = (const float*)d_in[6];
    const float* b1   = (const float*)d_in[7];
    const float* Wr1  = (const float*)d_in[8];
    const float* br1  = (const float*)d_in[9];
    const float* Wz1  = (const float*)d_in[10];
    const float* bz1  = (const float*)d_in[11];
    const float* Wh1  = (const float*)d_in[12];
    const float* bh1  = (const float*)d_in[13];
    const float* Wp2  = (const float*)d_in[14];
    const float* bp2  = (const float*)d_in[15];
    const float* W2   = (const float*)d_in[16];
    const float* as2  = (const float*)d_in[17];
    const float* ad2  = (const float*)d_in[18];
    const float* b2   = (const float*)d_in[19];
    const float* Wr2  = (const float*)d_in[20];
    const float* br2  = (const float*)d_in[21];
    const float* Wz2  = (const float*)d_in[22];
    const float* bz2  = (const float*)d_in[23];
    const float* Wh2  = (const float*)d_in[24];
    const float* bh2  = (const float*)d_in[25];
    const float* Wp3  = (const float*)d_in[26];
    const float* bp3  = (const float*)d_in[27];
    const float* W3   = (const float*)d_in[28];
    const float* as3  = (const float*)d_in[29];
    const float* ad3  = (const float*)d_in[30];
    const float* b3   = (const float*)d_in[31];
    const float* Wr3  = (const float*)d_in[32];
    const float* br3  = (const float*)d_in[33];
    const float* Wz3  = (const float*)d_in[34];
    const float* bz3  = (const float*)d_in[35];
    const float* Wh3  = (const float*)d_in[36];
    const float* bh3  = (const float*)d_in[37];

    const int Nn = in_sizes[0] / 128;   // 50000
    const int E  = in_sizes[1] / 2;     // 800000
    const int* srcp = ei;
    const int* dstp = ei + E;

    // ---------------- workspace layout (bf16-state) ----------------
    float* AS  = (float*)d_ws;                          // [N,8]
    float* AD  = AS + (size_t)Nn * 8;                   // [N,8]
    float* H3f = AD + (size_t)Nn * 8;                   // [N,64] fp32 (L3 h_in)
    float* Z3f = H3f + (size_t)Nn * 64;                 // [N,64] fp32 (L3 z)
    unsigned short* X0b  = (unsigned short*)(Z3f + (size_t)Nn * 64); // [N,256]
    unsigned short* XPb  = X0b + (size_t)Nn * 256;      // [N,256]
    unsigned short* Gb   = XPb + (size_t)Nn * 256;      // [N,256]
    unsigned short* RHb  = Gb  + (size_t)Nn * 256;      // [N,256]
    unsigned short* HINb = RHb + (size_t)Nn * 256;      // [N,128]
    unsigned short* Zb   = HINb + (size_t)Nn * 128;     // [N,256]
    unsigned short* wpool = Zb + (size_t)Nn * 256;
    unsigned short* Wtrc   = wpool;                     // 128*256
    unsigned short* W1c    = Wtrc   + 128 * 256;        // 256*256
    unsigned short* Wr1c   = W1c    + 256 * 256;        // 512*256
    unsigned short* Wz1c   = Wr1c   + 512 * 256;
    unsigned short* Wh1c   = Wz1c   + 512 * 256;
    unsigned short* Wp2W2c = Wh1c   + 512 * 256;        // 256*256 combined
    unsigned short* Wr2c   = Wp2W2c + 256 * 256;        // 256*128
    unsigned short* Wz2c   = Wr2c   + 256 * 128;
    unsigned short* Wh2c   = Wz2c   + 256 * 128;
    unsigned short* Wp3W3c = Wh2c   + 256 * 128;        // 128*128 combined
    unsigned short* Wr3c   = Wp3W3c + 128 * 128;        // 128*64
    unsigned short* Wz3c   = Wr3c   + 128 * 64;
    unsigned short* Wh3c   = Wz3c   + 128 * 64;
    int* ioff = (int*)(((size_t)(Wh3c + 128 * 64) + 15) & ~(size_t)15);
    int* cnt  = ioff + (Nn + 1);
    int* cur  = cnt + Nn;
    int* csr  = cur + Nn;

    dim3 blk(256);

    // ---------- all 15 weight conversions in ONE launch ----------
    {
        WPack p;
        const float* Ws[15]     = {W_tr, W1, Wr1, Wz1, Wh1,
                                   Wp2, W2, Wr2, Wz2, Wh2,
                                   Wp3, W3, Wr3, Wz3, Wh3};
        unsigned short* Wcs[15] = {Wtrc, W1c, Wr1c, Wz1c, Wh1c,
                                   Wp2W2c, Wp2W2c, Wr2c, Wz2c, Wh2c,
                                   Wp3W3c, Wp3W3c, Wr3c, Wz3c, Wh3c};
        int Ks[15]   = {128, 256, 512, 512, 512, 256, 256, 256, 256, 256, 128, 128, 128, 128, 128};
        int MoSs[15] = {256, 256, 256, 256, 256, 128, 128, 128, 128, 128, 64, 64, 64, 64, 64};
        int MoDs[15] = {256, 256, 256, 256, 256, 256, 256, 128, 128, 128, 128, 128, 64, 64, 64};
        int offs[15] = {0, 0, 0, 0, 0, 0, 128, 0, 0, 0, 0, 64, 0, 0, 0};
        for (int i = 0; i < 15; ++i) {
            p.W[i] = Ws[i]; p.Wc[i] = Wcs[i]; p.K[i] = Ks[i];
            p.MoS[i] = MoSs[i]; p.MoD[i] = MoDs[i]; p.off[i] = offs[i];
        }
        convW_all<<<dim3((512 * 256 + 255) / 256, 15), blk, 0, stream>>>(p);
    }

    // ---------- CSR build ----------
    hipMemsetAsync(cnt, 0, (size_t)Nn * 4, stream);
    hipMemsetAsync(cur, 0, (size_t)Nn * 4, stream);
    count_k<<<(E + 255) / 256, blk, 0, stream>>>(dstp, E, cnt);
    scan_k<<<1, 1024, 0, stream>>>(cnt, Nn, ioff);
    scatter_k<<<(E + 255) / 256, blk, 0, stream>>>(srcp, dstp, E, ioff, cur, csr);

    // ---------- stage 0: X0b = bf16(x @ W_tr + b_tr) ----------
    unsigned short* xb = Gb;   // Gb free until gather1
    conv_k<<<(int)(((long)Nn * 128 / 4 + 255) / 256), blk, 0, stream>>>(x, xb, (long)Nn * 128);
    gemm_t<128,0><<<gblocks(Nn, 256, 128), blk, 0, stream>>>(
        xb, 128, nullptr, 0, Wtrc, b_tr, nullptr, X0b, nullptr,
        nullptr, nullptr, nullptr, nullptr, Nn, 256);

    // ================= layer 1 (D=256, H=8, C=32) =================
    gemm_t<128,0><<<gblocks(Nn, 256, 128), blk, 0, stream>>>(
        X0b, 256, nullptr, 0, W1c, nullptr, nullptr, XPb, nullptr,
        nullptr, nullptr, nullptr, nullptr, Nn, 256);
    alpha_b<<<(Nn * 8 + 255) / 256, blk, 0, stream>>>(XPb, as1, ad1, AS, AD, Nn, 8, 32);
    launch_gather(ioff, csr, XPb, AS, AD, b1, Gb, Nn, 8, 32, 1, stream);
    gemm_rz<0><<<gblocks(Nn, 256, 64), blk, 0, stream>>>(
        Gb, 256, X0b, 256, Wr1c, Wz1c, br1, bz1, X0b, nullptr, RHb, Zb, nullptr, Nn, 256);
    gemm_t<128,3><<<gblocks(Nn, 256, 128), blk, 0, stream>>>(
        Gb, 256, RHb, 256, Wh1c, bh1, nullptr, XPb, nullptr,
        X0b, Zb, nullptr, nullptr, Nn, 256);
    // XPb holds x1 (bf16)

    // ================= layer 2 (D=128, H=4, C=32) =================
    gemm_t<128,4><<<gblocks(Nn, 256, 128), blk, 0, stream>>>(
        XPb, 256, nullptr, 0, Wp2W2c, bp2, nullptr, HINb, X0b,
        nullptr, nullptr, nullptr, nullptr, Nn, 256);
    alpha_b<<<(Nn * 4 + 255) / 256, blk, 0, stream>>>(X0b, as2, ad2, AS, AD, Nn, 4, 32);
    launch_gather(ioff, csr, X0b, AS, AD, b2, Gb, Nn, 4, 32, 1, stream);
    gemm_rz<0><<<gblocks(Nn, 128, 64), blk, 0, stream>>>(
        Gb, 128, HINb, 128, Wr2c, Wz2c, br2, bz2, HINb, nullptr, RHb, Zb, nullptr, Nn, 128);
    gemm_t<128,3><<<gblocks(Nn, 128, 128), blk, 0, stream>>>(
        Gb, 128, RHb, 128, Wh2c, bh2, nullptr, X0b, nullptr,
        HINb, Zb, nullptr, nullptr, Nn, 128);
    // X0b holds x2 (bf16)

    // ================= layer 3 (D=64, H=1, C=64, fp32 state) =================
    unsigned short* H3b  = HINb;                 // [N,64]
    unsigned short* XP3b = HINb + (size_t)Nn * 64;
    gemm_t<128,4><<<gblocks(Nn, 128, 128), blk, 0, stream>>>(
        X0b, 128, nullptr, 0, Wp3W3c, bp3, H3f, H3b, XP3b,
        nullptr, nullptr, nullptr, nullptr, Nn, 128);
    alpha_b<<<(Nn + 255) / 256, blk, 0, stream>>>(XP3b, as3, ad3, AS, AD, Nn, 1, 64);
    launch_gather(ioff, csr, XP3b, AS, AD, b3, Gb, Nn, 1, 64, 0, stream);
    gemm_rz<1><<<gblocks(Nn, 64, 64), blk, 0, stream>>>(
        Gb, 64, H3b, 64, Wr3c, Wz3c, br3, bz3, nullptr, H3f, RHb, nullptr, Z3f, Nn, 64);
    gemm_t<64,5><<<gblocks(Nn, 64, 64), blk, 0, stream>>>(
        Gb, 64, RHb, 64, Wh3c, bh3, (float*)d_out, nullptr, nullptr,
        nullptr, nullptr, H3f, Z3f, Nn, 64);
}